// Round 13
// baseline (424.904 us; speedup 1.0000x reference)
//
#include <hip/hip_runtime.h>
#include <hip/hip_bf16.h>
#include <hip/hip_fp16.h>
#include <math.h>

#define N_NODES 50000
#define N_EDGES 800000
#define IN_DIM 128
#define NHEAD 4
#define NREL 64
#define HC 256              // NHEAD * 64 (both layers: H*HID = H*OUT = 256)
#define NEG_SLOPE 0.2f
#define SCAN_B ((N_NODES + 255) / 256)   // 196 blocks

// async global->LDS, 16B per lane (zero VGPR staging; compiler never auto-emits)
__device__ __forceinline__ void load_lds16(const float* g, float* l) {
  __builtin_amdgcn_global_load_lds(
      (const __attribute__((address_space(1))) unsigned int*)g,
      (__attribute__((address_space(3))) unsigned int*)l, 16, 0, 0);
}

// ============ GEMM + fused alpha: 32x256 block, wave = 8 rows x 256 cols ======
// R12 diagnosis: inner loop was LDS-instruction-bound (8 broadcast ds_read_b32
// per kk per thread ~= 59us/CU — matches measured, K-independent). Fix: X is
// wave-uniform here (wave owns 8 rows), so X goes through the SCALAR unit
// (s_load, lgkmcnt) and feeds v_fma as the SGPR operand — zero LDS/VALU cost.
// Only W touches LDS (1 ds_read_b128/kk/thread). W double-buffered via
// global_load_lds with counted vmcnt(4).
__global__ __launch_bounds__(256) void gemm_xw_alpha(
    const float* __restrict__ X, const float* __restrict__ W,
    const float* __restrict__ a_s, const float* __restrict__ a_d,
    __half2* __restrict__ xs16, float* __restrict__ asrc, float* __restrict__ adst,
    int M, int K) {
  __shared__ __align__(16) float wbuf[2][16][256];   // [buf][kk][col] 16KB each
  const int t = threadIdx.x;
  const int wv = __builtin_amdgcn_readfirstlane(t >> 6);   // uniform wave id
  const int lane = t & 63;
  const int cc = lane * 4;                // this thread's 4 cols (0..255)
  const int row0 = blockIdx.x * 32;
  const int rbase = row0 + wv * 8;        // uniform: this wave's 8 rows

  // uniform row base pointers (clamped so OOB rows read row M-1, stores guarded)
  const float* Xr[8];
#pragma unroll
  for (int r = 0; r < 8; ++r) {
    int grow = rbase + r;
    grow = (grow < M) ? grow : (M - 1);
    Xr[r] = X + (size_t)grow * K;
  }

#define STAGE(BI, KB)                                                         \
  {                                                                           \
    _Pragma("unroll")                                                         \
    for (int j = 0; j < 4; ++j) {                                             \
      const int kk = wv * 4 + j;                                              \
      load_lds16(&W[(size_t)((KB) + kk) * HC + lane * 4], &wbuf[BI][kk][0]);  \
    }                                                                         \
  }

  float acc[8][4];
#pragma unroll
  for (int r = 0; r < 8; ++r)
#pragma unroll
    for (int c = 0; c < 4; ++c) acc[r][c] = 0.f;

  STAGE(0, 0);                            // prologue: W tile 0 in flight
  const int nt = K >> 4;
  for (int tg = 0; tg < nt; ++tg) {
    const int cur = tg & 1;
    const int kb = tg * 16;
    if (tg + 1 < nt) {
      STAGE(cur ^ 1, kb + 16);            // issue next W tile (async)
      asm volatile("s_waitcnt vmcnt(4)" ::: "memory");   // this tile landed
    } else {
      asm volatile("s_waitcnt vmcnt(0)" ::: "memory");
    }
    __builtin_amdgcn_s_barrier();         // all waves' tile loads visible
    __builtin_amdgcn_sched_barrier(0);
#pragma unroll
    for (int q = 0; q < 4; ++q) {         // 4 kk-quads of 4
      // uniform X values for this quad: 8 rows x 4 kk -> SGPRs via s_load
      float xr[8][4];
#pragma unroll
      for (int r = 0; r < 8; ++r)
#pragma unroll
        for (int j = 0; j < 4; ++j) xr[r][j] = Xr[r][kb + q * 4 + j];
#pragma unroll
      for (int j = 0; j < 4; ++j) {
        const float4 w4 = *(const float4*)&wbuf[cur][q * 4 + j][cc];
#pragma unroll
        for (int r = 0; r < 8; ++r) {
          acc[r][0] += xr[r][j] * w4.x;
          acc[r][1] += xr[r][j] * w4.y;
          acc[r][2] += xr[r][j] * w4.z;
          acc[r][3] += xr[r][j] * w4.w;
        }
      }
    }
    asm volatile("" ::: "memory");
    __builtin_amdgcn_s_barrier();         // all reads of buf[cur] done
  }
#undef STAGE

  const float4 as4 = *(const float4*)&a_s[cc];
  const float4 ad4 = *(const float4*)&a_d[cc];
  const int head = lane >> 4;             // head owning cols cc..cc+3
#pragma unroll
  for (int r = 0; r < 8; ++r) {
    const int row = rbase + r;
    const bool ok = row < M;
    if (ok) {
      __half2 q0 = __floats2half2_rn(acc[r][0], acc[r][1]);
      __half2 q1 = __floats2half2_rn(acc[r][2], acc[r][3]);
      uint2 qq = make_uint2(*(unsigned*)&q0, *(unsigned*)&q1);
      *(uint2*)&xs16[((size_t)row * HC + cc) >> 1] = qq;
    }
    float sp = acc[r][0] * as4.x + acc[r][1] * as4.y + acc[r][2] * as4.z + acc[r][3] * as4.w;
    float dp = acc[r][0] * ad4.x + acc[r][1] * ad4.y + acc[r][2] * ad4.z + acc[r][3] * ad4.w;
#pragma unroll
    for (int off = 1; off < 16; off <<= 1) {
      sp += __shfl_xor(sp, off);
      dp += __shfl_xor(dp, off);
    }
    if ((lane & 15) == 0 && ok) {
      asrc[row * NHEAD + head] = sp;
      adst[row * NHEAD + head] = dp;
    }
  }
}

// ============ per-relation alpha_e tables for BOTH layers ============
__global__ __launch_bounds__(256) void relalpha2_kernel(
    const float* __restrict__ rel1, const float* __restrict__ We1, const float* __restrict__ ae1,
    const float* __restrict__ rel2, const float* __restrict__ We2, const float* __restrict__ ae2,
    float* __restrict__ tab1, float* __restrict__ tab2) {
  const int layer = blockIdx.x >> 6;
  const int r = blockIdx.x & 63;
  const float* rel = layer ? rel2 : rel1;
  const float* We  = layer ? We2  : We1;
  const float* ae  = layer ? ae2  : ae1;
  float* tab       = layer ? tab2 : tab1;
  const int K      = layer ? 64   : IN_DIM;
  int t = threadIdx.x;
  float acc = 0.f;
  for (int k = 0; k < K; ++k) acc += rel[(size_t)r * K + k] * We[(size_t)k * HC + t];
  int h = t >> 6, lane = t & 63;
  float p = acc * ae[t];
#pragma unroll
  for (int off = 32; off > 0; off >>= 1) p += __shfl_down(p, off);
  if (lane == 0) tab[r * NHEAD + h] = p;
}

// ============ CSR build ============
__global__ __launch_bounds__(256) void hist_kernel(
    const int* __restrict__ dst, int* __restrict__ deg) {
  int e = blockIdx.x * blockDim.x + threadIdx.x;
  if (e < N_EDGES) atomicAdd(&deg[dst[e]], 1);
}

__global__ __launch_bounds__(256) void block_sum_kernel(
    const int* __restrict__ deg, int* __restrict__ bsum) {
  int i = blockIdx.x * 256 + threadIdx.x;
  int v = (i < N_NODES) ? deg[i] : 0;
#pragma unroll
  for (int off = 32; off > 0; off >>= 1) v += __shfl_down(v, off);
  __shared__ int w[4];
  if ((threadIdx.x & 63) == 0) w[threadIdx.x >> 6] = v;
  __syncthreads();
  if (threadIdx.x == 0) bsum[blockIdx.x] = w[0] + w[1] + w[2] + w[3];
}

__global__ __launch_bounds__(256) void scan_bsum_kernel(
    const int* __restrict__ bsum, int* __restrict__ boff) {
  __shared__ int s[256];
  int t = threadIdx.x;
  int v = (t < SCAN_B) ? bsum[t] : 0;
  s[t] = v;
  __syncthreads();
  for (int off = 1; off < 256; off <<= 1) {
    int u = (t >= off) ? s[t - off] : 0;
    __syncthreads();
    s[t] += u;
    __syncthreads();
  }
  boff[t] = (t == 0) ? 0 : s[t - 1];
}

__global__ __launch_bounds__(256) void scan_final_kernel(
    const int* __restrict__ deg, const int* __restrict__ boff,
    int* __restrict__ rowptr, int* __restrict__ cursor) {
  __shared__ int s[256];
  int t = threadIdx.x;
  int i = blockIdx.x * 256 + t;
  int v = (i < N_NODES) ? deg[i] : 0;
  s[t] = v;
  __syncthreads();
  for (int off = 1; off < 256; off <<= 1) {
    int u = (t >= off) ? s[t - off] : 0;
    __syncthreads();
    s[t] += u;
    __syncthreads();
  }
  int excl = boff[blockIdx.x] + s[t] - v;
  if (i < N_NODES) {
    rowptr[i] = excl;
    cursor[i] = excl;
  }
  if (t == 0 && blockIdx.x == 0) rowptr[N_NODES] = N_EDGES;
}

__global__ __launch_bounds__(256) void fill_kernel(
    const int* __restrict__ src, const int* __restrict__ dst,
    const int* __restrict__ etype, int* __restrict__ cursor,
    int2* __restrict__ csr_pack) {
  int e = blockIdx.x * blockDim.x + threadIdx.x;
  if (e >= N_EDGES) return;
  int d = dst[e];
  int i = atomicAdd(&cursor[d], 1);
  csr_pack[i] = make_int2(src[e], etype[e]);
}

// ============ fused no-max softmax + fp16 gather: ONE WAVE PER NODE ============
__global__ __launch_bounds__(256) void gat_node_kernel(
    const int* __restrict__ rowptr, const int2* __restrict__ csr,
    const float* __restrict__ asrc, const float* __restrict__ adst,
    const float* __restrict__ tab, const __half2* __restrict__ xs16,
    const float* __restrict__ b, float* __restrict__ out, int relu) {
  const int n = (blockIdx.x * blockDim.x + threadIdx.x) >> 6;
  if (n >= N_NODES) return;
  const int lane = threadIdx.x & 63;
  const int hh = lane >> 4;               // head of this lane's 4 cols
  const int cbase = lane << 2;
  const int i0 = rowptr[n], i1 = rowptr[n + 1];
  const float adn = adst[n * NHEAD + hh];
  const float treg = tab[lane * NHEAD + hh];   // lane = rel id (NREL==64)

  float4 acc = make_float4(0.f, 0.f, 0.f, 0.f);
  float den = 0.f;
  int i = i0;
  for (; i + 4 <= i1; i += 4) {
    const int2 p0 = csr[i], p1 = csr[i + 1], p2 = csr[i + 2], p3 = csr[i + 3];
    float l0 = asrc[p0.x * NHEAD + hh] + adn + __shfl(treg, p0.y);
    float l1 = asrc[p1.x * NHEAD + hh] + adn + __shfl(treg, p1.y);
    float l2 = asrc[p2.x * NHEAD + hh] + adn + __shfl(treg, p2.y);
    float l3 = asrc[p3.x * NHEAD + hh] + adn + __shfl(treg, p3.y);
    const uint2 q0 = *(const uint2*)&xs16[((size_t)p0.x * HC + cbase) >> 1];
    const uint2 q1 = *(const uint2*)&xs16[((size_t)p1.x * HC + cbase) >> 1];
    const uint2 q2 = *(const uint2*)&xs16[((size_t)p2.x * HC + cbase) >> 1];
    const uint2 q3 = *(const uint2*)&xs16[((size_t)p3.x * HC + cbase) >> 1];
    l0 = (l0 >= 0.f) ? l0 : NEG_SLOPE * l0;
    l1 = (l1 >= 0.f) ? l1 : NEG_SLOPE * l1;
    l2 = (l2 >= 0.f) ? l2 : NEG_SLOPE * l2;
    l3 = (l3 >= 0.f) ? l3 : NEG_SLOPE * l3;
    const float w0 = __expf(l0), w1 = __expf(l1), w2 = __expf(l2), w3 = __expf(l3);
    den += (w0 + w1) + (w2 + w3);
    const float2 a0 = __half22float2(*(const __half2*)&q0.x), b0 = __half22float2(*(const __half2*)&q0.y);
    const float2 a1 = __half22float2(*(const __half2*)&q1.x), b1 = __half22float2(*(const __half2*)&q1.y);
    const float2 a2 = __half22float2(*(const __half2*)&q2.x), b2 = __half22float2(*(const __half2*)&q2.y);
    const float2 a3 = __half22float2(*(const __half2*)&q3.x), b3 = __half22float2(*(const __half2*)&q3.y);
    acc.x += w0 * a0.x + w1 * a1.x + w2 * a2.x + w3 * a3.x;
    acc.y += w0 * a0.y + w1 * a1.y + w2 * a2.y + w3 * a3.y;
    acc.z += w0 * b0.x + w1 * b1.x + w2 * b2.x + w3 * b3.x;
    acc.w += w0 * b0.y + w1 * b1.y + w2 * b2.y + w3 * b3.y;
  }
  for (; i < i1; ++i) {
    const int2 p = csr[i];
    float l = asrc[p.x * NHEAD + hh] + adn + __shfl(treg, p.y);
    l = (l >= 0.f) ? l : NEG_SLOPE * l;
    const float w = __expf(l);
    const uint2 q = *(const uint2*)&xs16[((size_t)p.x * HC + cbase) >> 1];
    const float2 a = __half22float2(*(const __half2*)&q.x);
    const float2 c = __half22float2(*(const __half2*)&q.y);
    den += w;
    acc.x += w * a.x; acc.y += w * a.y; acc.z += w * c.x; acc.w += w * c.y;
  }

  const float rd = (den > 0.f) ? (0.25f / den) : 0.f;
  float4 y = make_float4(acc.x * rd, acc.y * rd, acc.z * rd, acc.w * rd);
#pragma unroll
  for (int off = 16; off < 64; off <<= 1) {
    y.x += __shfl_xor(y.x, off);
    y.y += __shfl_xor(y.y, off);
    y.z += __shfl_xor(y.z, off);
    y.w += __shfl_xor(y.w, off);
  }
  if (lane < 16) {
    const float4 bb = *(const float4*)&b[lane * 4];
    y.x += bb.x; y.y += bb.y; y.z += bb.z; y.w += bb.w;
    if (relu) {
      y.x = fmaxf(y.x, 0.f); y.y = fmaxf(y.y, 0.f);
      y.z = fmaxf(y.z, 0.f); y.w = fmaxf(y.w, 0.f);
    }
    *(float4*)&out[(size_t)n * 64 + lane * 4] = y;
  }
}

extern "C" void kernel_launch(void* const* d_in, const int* in_sizes, int n_in,
                              void* d_out, int out_size, void* d_ws, size_t ws_size,
                              hipStream_t stream) {
  const float* x   = (const float*)d_in[0];
  const int* eidx  = (const int*)d_in[1];
  const int* etype = (const int*)d_in[2];
  const float* rel1 = (const float*)d_in[3];
  const float* W1   = (const float*)d_in[4];
  const float* We1  = (const float*)d_in[5];
  const float* as1  = (const float*)d_in[6];
  const float* ad1  = (const float*)d_in[7];
  const float* ae1  = (const float*)d_in[8];
  const float* b1   = (const float*)d_in[9];
  const float* rel2 = (const float*)d_in[10];
  const float* W2   = (const float*)d_in[11];
  const float* We2  = (const float*)d_in[12];
  const float* as2  = (const float*)d_in[13];
  const float* ad2  = (const float*)d_in[14];
  const float* ae2  = (const float*)d_in[15];
  const float* b2   = (const float*)d_in[16];
  const int* src = eidx;
  const int* dst = eidx + N_EDGES;

  // ---- workspace layout ----
  __half2* xs16 = (__half2*)d_ws;                         // N*256 halves
  float* fbase = (float*)((char*)d_ws + (size_t)N_NODES * HC * 2);
  float* asrc = fbase;                                    // N*4
  float* adst = asrc + (size_t)N_NODES * NHEAD;           // N*4
  float* tab1 = adst + (size_t)N_NODES * NHEAD;           // R*4
  float* tab2 = tab1 + NREL * NHEAD;                      // R*4
  float* h1   = tab2 + NREL * NHEAD;                      // N*64
  int* ip = (int*)(h1 + (size_t)N_NODES * 64);
  int* deg     = ip;                                      // N
  int* rowptr  = deg + N_NODES;                           // N+1
  int* cursor  = rowptr + N_NODES + 1;                    // N
  int2* csr    = (int2*)(cursor + N_NODES + 1);           // E int2
  int* bsum    = (int*)(csr + N_EDGES);                   // 256
  int* boff    = bsum + 256;                              // 256

  // ---- CSR build + both alpha_e tables (layer-independent) ----
  hipMemsetAsync(deg, 0, N_NODES * sizeof(int), stream);
  hist_kernel<<<(N_EDGES + 255) / 256, 256, 0, stream>>>(dst, deg);
  block_sum_kernel<<<SCAN_B, 256, 0, stream>>>(deg, bsum);
  scan_bsum_kernel<<<1, 256, 0, stream>>>(bsum, boff);
  scan_final_kernel<<<SCAN_B, 256, 0, stream>>>(deg, boff, rowptr, cursor);
  fill_kernel<<<(N_EDGES + 255) / 256, 256, 0, stream>>>(src, dst, etype, cursor, csr);
  relalpha2_kernel<<<2 * NREL, 256, 0, stream>>>(rel1, We1, ae1, rel2, We2, ae2, tab1, tab2);

  const dim3 gemm_grid((N_NODES + 31) / 32);
  const int GB = (N_NODES * 64 + 255) / 256;   // one wave per node

  // ================= layer 1 =================
  gemm_xw_alpha<<<gemm_grid, 256, 0, stream>>>(x, W1, as1, ad1, xs16, asrc, adst, N_NODES, IN_DIM);
  gat_node_kernel<<<GB, 256, 0, stream>>>(rowptr, csr, asrc, adst, tab1, xs16, b1, h1, 1);

  // ================= layer 2 =================
  gemm_xw_alpha<<<gemm_grid, 256, 0, stream>>>(h1, W2, as2, ad2, xs16, asrc, adst, N_NODES, 64);
  gat_node_kernel<<<GB, 256, 0, stream>>>(rowptr, csr, asrc, adst, tab2, xs16, b2, (float*)d_out, 0);
}

// Round 14
// 359.694 us; speedup vs baseline: 1.1813x; 1.1813x over previous
//
#include <hip/hip_runtime.h>
#include <hip/hip_bf16.h>
#include <hip/hip_fp16.h>
#include <math.h>

#define N_NODES 50000
#define N_EDGES 800000
#define IN_DIM 128
#define NHEAD 4
#define NREL 64
#define HC 256              // NHEAD * 64 (both layers: H*HID = H*OUT = 256)
#define NEG_SLOPE 0.2f
#define SCAN_B ((N_NODES + 255) / 256)   // 196 blocks

// async global->LDS, 16B per lane (zero VGPR staging; compiler never auto-emits)
__device__ __forceinline__ void load_lds16(const float* g, float* l) {
  __builtin_amdgcn_global_load_lds(
      (const __attribute__((address_space(1))) unsigned int*)g,
      (__attribute__((address_space(3))) unsigned int*)l, 16, 0, 0);
}

// ============ GEMM + fused alpha, 64x128 tile, BK=16, 8x4/thread ============
// R12 structure (double-buffered global_load_lds, counted vmcnt(3)) with the
// inner loop re-blocked into k-QUADS: one broadcast ds_read_b128 per row per
// 4 kk (reused 4x) instead of 8 ds_read_b32 per kk. LDS instructions/tile:
// 144 -> 48. R12's cost was LDS-instruction-rate (~75us/CU model matched the
// K-independent ~60us measured), not bandwidth. R13's scalar-unit attempt is
// reverted (compiler emitted per-lane VMEM, 2x regression).
__global__ __launch_bounds__(256) void gemm_xw_alpha(
    const float* __restrict__ X, const float* __restrict__ W,
    const float* __restrict__ a_s, const float* __restrict__ a_d,
    __half2* __restrict__ xs16, float* __restrict__ asrc, float* __restrict__ adst,
    int M, int K) {
  __shared__ __align__(16) float wbuf[2][16][128];   // [buf][kk][col] 8KB each
  __shared__ __align__(16) float xbuf[2][64][16];    // [buf][row][kk]  4KB each
  const int t = threadIdx.x;
  const int wv = t >> 6;
  const int l  = t & 63;
  const int rg = l >> 5;                  // row-half within wave
  const int cg = l & 31;                  // col-group
  const int cc = cg * 4;                  // local col
  const int rbase = wv * 16 + rg * 8;     // local row base (8 rows/thread)
  const int row0 = blockIdx.x * 64;
  const int c0 = blockIdx.y * 128;

#define STAGE(BI, KB)                                                          \
  {                                                                            \
    _Pragma("unroll")                                                          \
    for (int j = 0; j < 2; ++j) {                                              \
      const int wrow = wv * 4 + j * 2 + (l >> 5);                              \
      load_lds16(&W[(size_t)((KB) + wrow) * HC + c0 + (l & 31) * 4],           \
                 &wbuf[BI][wv * 4 + j * 2][0]);                                \
    }                                                                          \
    {                                                                          \
      const int xrow = wv * 16 + (l >> 2);                                     \
      const int grow = min(row0 + xrow, M - 1);                                \
      load_lds16(&X[(size_t)grow * K + (KB) + (l & 3) * 4],                    \
                 &xbuf[BI][wv * 16][0]);                                       \
    }                                                                          \
  }

  float acc[8][4];
#pragma unroll
  for (int r = 0; r < 8; ++r)
#pragma unroll
    for (int c = 0; c < 4; ++c) acc[r][c] = 0.f;

  STAGE(0, 0);                            // prologue: tile 0 in flight
  const int nt = K >> 4;
  for (int tg = 0; tg < nt; ++tg) {
    const int cur = tg & 1;
    if (tg + 1 < nt) {
      STAGE(cur ^ 1, (tg + 1) * 16);      // issue next tile (async)
      asm volatile("s_waitcnt vmcnt(3)" ::: "memory");   // this tile landed
    } else {
      asm volatile("s_waitcnt vmcnt(0)" ::: "memory");
    }
    __builtin_amdgcn_s_barrier();         // all waves' tile-tg loads visible
    __builtin_amdgcn_sched_barrier(0);
#pragma unroll
    for (int q = 0; q < 4; ++q) {         // 4 k-quads of 4 kk
      const float4 wq0 = *(const float4*)&wbuf[cur][q * 4 + 0][cc];
      const float4 wq1 = *(const float4*)&wbuf[cur][q * 4 + 1][cc];
      const float4 wq2 = *(const float4*)&wbuf[cur][q * 4 + 2][cc];
      const float4 wq3 = *(const float4*)&wbuf[cur][q * 4 + 3][cc];
#pragma unroll
      for (int r = 0; r < 8; ++r) {
        const float4 x4 = *(const float4*)&xbuf[cur][rbase + r][q * 4]; // broadcast
        acc[r][0] += x4.x * wq0.x + x4.y * wq1.x + x4.z * wq2.x + x4.w * wq3.x;
        acc[r][1] += x4.x * wq0.y + x4.y * wq1.y + x4.z * wq2.y + x4.w * wq3.y;
        acc[r][2] += x4.x * wq0.z + x4.y * wq1.z + x4.z * wq2.z + x4.w * wq3.z;
        acc[r][3] += x4.x * wq0.w + x4.y * wq1.w + x4.z * wq2.w + x4.w * wq3.w;
      }
    }
    asm volatile("" ::: "memory");
    __builtin_amdgcn_s_barrier();         // all reads of buf[cur] done
  }
#undef STAGE

  const float4 as4 = *(const float4*)&a_s[c0 + cc];
  const float4 ad4 = *(const float4*)&a_d[c0 + cc];
  const int head = blockIdx.y * 2 + (cg >> 4);
#pragma unroll
  for (int r = 0; r < 8; ++r) {
    const int row = row0 + rbase + r;
    const bool ok = row < M;
    if (ok) {
      __half2 q0 = __floats2half2_rn(acc[r][0], acc[r][1]);
      __half2 q1 = __floats2half2_rn(acc[r][2], acc[r][3]);
      uint2 qq = make_uint2(*(unsigned*)&q0, *(unsigned*)&q1);
      *(uint2*)&xs16[((size_t)row * HC + c0 + cc) >> 1] = qq;
    }
    float sp = acc[r][0] * as4.x + acc[r][1] * as4.y + acc[r][2] * as4.z + acc[r][3] * as4.w;
    float dp = acc[r][0] * ad4.x + acc[r][1] * ad4.y + acc[r][2] * ad4.z + acc[r][3] * ad4.w;
#pragma unroll
    for (int off = 1; off < 16; off <<= 1) {
      sp += __shfl_xor(sp, off);
      dp += __shfl_xor(dp, off);
    }
    if ((cg & 15) == 0 && ok) {
      asrc[row * NHEAD + head] = sp;
      adst[row * NHEAD + head] = dp;
    }
  }
}

// ============ per-relation alpha_e tables for BOTH layers ============
__global__ __launch_bounds__(256) void relalpha2_kernel(
    const float* __restrict__ rel1, const float* __restrict__ We1, const float* __restrict__ ae1,
    const float* __restrict__ rel2, const float* __restrict__ We2, const float* __restrict__ ae2,
    float* __restrict__ tab1, float* __restrict__ tab2) {
  const int layer = blockIdx.x >> 6;
  const int r = blockIdx.x & 63;
  const float* rel = layer ? rel2 : rel1;
  const float* We  = layer ? We2  : We1;
  const float* ae  = layer ? ae2  : ae1;
  float* tab       = layer ? tab2 : tab1;
  const int K      = layer ? 64   : IN_DIM;
  int t = threadIdx.x;
  float acc = 0.f;
  for (int k = 0; k < K; ++k) acc += rel[(size_t)r * K + k] * We[(size_t)k * HC + t];
  int h = t >> 6, lane = t & 63;
  float p = acc * ae[t];
#pragma unroll
  for (int off = 32; off > 0; off >>= 1) p += __shfl_down(p, off);
  if (lane == 0) tab[r * NHEAD + h] = p;
}

// ============ CSR build ============
__global__ __launch_bounds__(256) void hist_kernel(
    const int* __restrict__ dst, int* __restrict__ deg) {
  int e = blockIdx.x * blockDim.x + threadIdx.x;
  if (e < N_EDGES) atomicAdd(&deg[dst[e]], 1);
}

__global__ __launch_bounds__(256) void block_sum_kernel(
    const int* __restrict__ deg, int* __restrict__ bsum) {
  int i = blockIdx.x * 256 + threadIdx.x;
  int v = (i < N_NODES) ? deg[i] : 0;
#pragma unroll
  for (int off = 32; off > 0; off >>= 1) v += __shfl_down(v, off);
  __shared__ int w[4];
  if ((threadIdx.x & 63) == 0) w[threadIdx.x >> 6] = v;
  __syncthreads();
  if (threadIdx.x == 0) bsum[blockIdx.x] = w[0] + w[1] + w[2] + w[3];
}

__global__ __launch_bounds__(256) void scan_bsum_kernel(
    const int* __restrict__ bsum, int* __restrict__ boff) {
  __shared__ int s[256];
  int t = threadIdx.x;
  int v = (t < SCAN_B) ? bsum[t] : 0;
  s[t] = v;
  __syncthreads();
  for (int off = 1; off < 256; off <<= 1) {
    int u = (t >= off) ? s[t - off] : 0;
    __syncthreads();
    s[t] += u;
    __syncthreads();
  }
  boff[t] = (t == 0) ? 0 : s[t - 1];
}

__global__ __launch_bounds__(256) void scan_final_kernel(
    const int* __restrict__ deg, const int* __restrict__ boff,
    int* __restrict__ rowptr, int* __restrict__ cursor) {
  __shared__ int s[256];
  int t = threadIdx.x;
  int i = blockIdx.x * 256 + t;
  int v = (i < N_NODES) ? deg[i] : 0;
  s[t] = v;
  __syncthreads();
  for (int off = 1; off < 256; off <<= 1) {
    int u = (t >= off) ? s[t - off] : 0;
    __syncthreads();
    s[t] += u;
    __syncthreads();
  }
  int excl = boff[blockIdx.x] + s[t] - v;
  if (i < N_NODES) {
    rowptr[i] = excl;
    cursor[i] = excl;
  }
  if (t == 0 && blockIdx.x == 0) rowptr[N_NODES] = N_EDGES;
}

__global__ __launch_bounds__(256) void fill_kernel(
    const int* __restrict__ src, const int* __restrict__ dst,
    const int* __restrict__ etype, int* __restrict__ cursor,
    int2* __restrict__ csr_pack) {
  int e = blockIdx.x * blockDim.x + threadIdx.x;
  if (e >= N_EDGES) return;
  int d = dst[e];
  int i = atomicAdd(&cursor[d], 1);
  csr_pack[i] = make_int2(src[e], etype[e]);
}

// ============ fused no-max softmax + fp16 gather: ONE WAVE PER NODE ============
__global__ __launch_bounds__(256) void gat_node_kernel(
    const int* __restrict__ rowptr, const int2* __restrict__ csr,
    const float* __restrict__ asrc, const float* __restrict__ adst,
    const float* __restrict__ tab, const __half2* __restrict__ xs16,
    const float* __restrict__ b, float* __restrict__ out, int relu) {
  const int n = (blockIdx.x * blockDim.x + threadIdx.x) >> 6;
  if (n >= N_NODES) return;
  const int lane = threadIdx.x & 63;
  const int hh = lane >> 4;               // head of this lane's 4 cols
  const int cbase = lane << 2;
  const int i0 = rowptr[n], i1 = rowptr[n + 1];
  const float adn = adst[n * NHEAD + hh];
  const float treg = tab[lane * NHEAD + hh];   // lane = rel id (NREL==64)

  float4 acc = make_float4(0.f, 0.f, 0.f, 0.f);
  float den = 0.f;
  int i = i0;
  for (; i + 4 <= i1; i += 4) {
    const int2 p0 = csr[i], p1 = csr[i + 1], p2 = csr[i + 2], p3 = csr[i + 3];
    float l0 = asrc[p0.x * NHEAD + hh] + adn + __shfl(treg, p0.y);
    float l1 = asrc[p1.x * NHEAD + hh] + adn + __shfl(treg, p1.y);
    float l2 = asrc[p2.x * NHEAD + hh] + adn + __shfl(treg, p2.y);
    float l3 = asrc[p3.x * NHEAD + hh] + adn + __shfl(treg, p3.y);
    const uint2 q0 = *(const uint2*)&xs16[((size_t)p0.x * HC + cbase) >> 1];
    const uint2 q1 = *(const uint2*)&xs16[((size_t)p1.x * HC + cbase) >> 1];
    const uint2 q2 = *(const uint2*)&xs16[((size_t)p2.x * HC + cbase) >> 1];
    const uint2 q3 = *(const uint2*)&xs16[((size_t)p3.x * HC + cbase) >> 1];
    l0 = (l0 >= 0.f) ? l0 : NEG_SLOPE * l0;
    l1 = (l1 >= 0.f) ? l1 : NEG_SLOPE * l1;
    l2 = (l2 >= 0.f) ? l2 : NEG_SLOPE * l2;
    l3 = (l3 >= 0.f) ? l3 : NEG_SLOPE * l3;
    const float w0 = __expf(l0), w1 = __expf(l1), w2 = __expf(l2), w3 = __expf(l3);
    den += (w0 + w1) + (w2 + w3);
    const float2 a0 = __half22float2(*(const __half2*)&q0.x), b0 = __half22float2(*(const __half2*)&q0.y);
    const float2 a1 = __half22float2(*(const __half2*)&q1.x), b1 = __half22float2(*(const __half2*)&q1.y);
    const float2 a2 = __half22float2(*(const __half2*)&q2.x), b2 = __half22float2(*(const __half2*)&q2.y);
    const float2 a3 = __half22float2(*(const __half2*)&q3.x), b3 = __half22float2(*(const __half2*)&q3.y);
    acc.x += w0 * a0.x + w1 * a1.x + w2 * a2.x + w3 * a3.x;
    acc.y += w0 * a0.y + w1 * a1.y + w2 * a2.y + w3 * a3.y;
    acc.z += w0 * b0.x + w1 * b1.x + w2 * b2.x + w3 * b3.x;
    acc.w += w0 * b0.y + w1 * b1.y + w2 * b2.y + w3 * b3.y;
  }
  for (; i < i1; ++i) {
    const int2 p = csr[i];
    float l = asrc[p.x * NHEAD + hh] + adn + __shfl(treg, p.y);
    l = (l >= 0.f) ? l : NEG_SLOPE * l;
    const float w = __expf(l);
    const uint2 q = *(const uint2*)&xs16[((size_t)p.x * HC + cbase) >> 1];
    const float2 a = __half22float2(*(const __half2*)&q.x);
    const float2 c = __half22float2(*(const __half2*)&q.y);
    den += w;
    acc.x += w * a.x; acc.y += w * a.y; acc.z += w * c.x; acc.w += w * c.y;
  }

  const float rd = (den > 0.f) ? (0.25f / den) : 0.f;
  float4 y = make_float4(acc.x * rd, acc.y * rd, acc.z * rd, acc.w * rd);
#pragma unroll
  for (int off = 16; off < 64; off <<= 1) {
    y.x += __shfl_xor(y.x, off);
    y.y += __shfl_xor(y.y, off);
    y.z += __shfl_xor(y.z, off);
    y.w += __shfl_xor(y.w, off);
  }
  if (lane < 16) {
    const float4 bb = *(const float4*)&b[lane * 4];
    y.x += bb.x; y.y += bb.y; y.z += bb.z; y.w += bb.w;
    if (relu) {
      y.x = fmaxf(y.x, 0.f); y.y = fmaxf(y.y, 0.f);
      y.z = fmaxf(y.z, 0.f); y.w = fmaxf(y.w, 0.f);
    }
    *(float4*)&out[(size_t)n * 64 + lane * 4] = y;
  }
}

extern "C" void kernel_launch(void* const* d_in, const int* in_sizes, int n_in,
                              void* d_out, int out_size, void* d_ws, size_t ws_size,
                              hipStream_t stream) {
  const float* x   = (const float*)d_in[0];
  const int* eidx  = (const int*)d_in[1];
  const int* etype = (const int*)d_in[2];
  const float* rel1 = (const float*)d_in[3];
  const float* W1   = (const float*)d_in[4];
  const float* We1  = (const float*)d_in[5];
  const float* as1  = (const float*)d_in[6];
  const float* ad1  = (const float*)d_in[7];
  const float* ae1  = (const float*)d_in[8];
  const float* b1   = (const float*)d_in[9];
  const float* rel2 = (const float*)d_in[10];
  const float* W2   = (const float*)d_in[11];
  const float* We2  = (const float*)d_in[12];
  const float* as2  = (const float*)d_in[13];
  const float* ad2  = (const float*)d_in[14];
  const float* ae2  = (const float*)d_in[15];
  const float* b2   = (const float*)d_in[16];
  const int* src = eidx;
  const int* dst = eidx + N_EDGES;

  // ---- workspace layout ----
  __half2* xs16 = (__half2*)d_ws;                         // N*256 halves
  float* fbase = (float*)((char*)d_ws + (size_t)N_NODES * HC * 2);
  float* asrc = fbase;                                    // N*4
  float* adst = asrc + (size_t)N_NODES * NHEAD;           // N*4
  float* tab1 = adst + (size_t)N_NODES * NHEAD;           // R*4
  float* tab2 = tab1 + NREL * NHEAD;                      // R*4
  float* h1   = tab2 + NREL * NHEAD;                      // N*64
  int* ip = (int*)(h1 + (size_t)N_NODES * 64);
  int* deg     = ip;                                      // N
  int* rowptr  = deg + N_NODES;                           // N+1
  int* cursor  = rowptr + N_NODES + 1;                    // N
  int2* csr    = (int2*)(cursor + N_NODES + 1);           // E int2
  int* bsum    = (int*)(csr + N_EDGES);                   // 256
  int* boff    = bsum + 256;                              // 256

  // ---- CSR build + both alpha_e tables (layer-independent) ----
  hipMemsetAsync(deg, 0, N_NODES * sizeof(int), stream);
  hist_kernel<<<(N_EDGES + 255) / 256, 256, 0, stream>>>(dst, deg);
  block_sum_kernel<<<SCAN_B, 256, 0, stream>>>(deg, bsum);
  scan_bsum_kernel<<<1, 256, 0, stream>>>(bsum, boff);
  scan_final_kernel<<<SCAN_B, 256, 0, stream>>>(deg, boff, rowptr, cursor);
  fill_kernel<<<(N_EDGES + 255) / 256, 256, 0, stream>>>(src, dst, etype, cursor, csr);
  relalpha2_kernel<<<2 * NREL, 256, 0, stream>>>(rel1, We1, ae1, rel2, We2, ae2, tab1, tab2);

  const dim3 gemm_grid((N_NODES + 63) / 64, 2);
  const int GB = (N_NODES * 64 + 255) / 256;   // one wave per node

  // ================= layer 1 =================
  gemm_xw_alpha<<<gemm_grid, 256, 0, stream>>>(x, W1, as1, ad1, xs16, asrc, adst, N_NODES, IN_DIM);
  gat_node_kernel<<<GB, 256, 0, stream>>>(rowptr, csr, asrc, adst, tab1, xs16, b1, h1, 1);

  // ================= layer 2 =================
  gemm_xw_alpha<<<gemm_grid, 256, 0, stream>>>(h1, W2, as2, ad2, xs16, asrc, adst, N_NODES, 64);
  gat_node_kernel<<<GB, 256, 0, stream>>>(rowptr, csr, asrc, adst, tab2, xs16, b2, (float*)d_out, 0);
}

// Round 15
// 318.618 us; speedup vs baseline: 1.3336x; 1.1289x over previous
//
#include <hip/hip_runtime.h>
#include <hip/hip_bf16.h>
#include <hip/hip_fp16.h>
#include <math.h>

#define N_NODES 50000
#define N_EDGES 800000
#define IN_DIM 128
#define NHEAD 4
#define NREL 64
#define HC 256              // NHEAD * 64 (both layers: H*HID = H*OUT = 256)
#define NEG_SLOPE 0.2f
#define SCAN_B ((N_NODES + 255) / 256)   // 196 blocks

using short8 = __attribute__((ext_vector_type(8))) short;   // 8 bf16 (4 VGPRs)
using f32x4  = __attribute__((ext_vector_type(4))) float;

// async global->LDS, 16B per lane (zero VGPR staging)
__device__ __forceinline__ void load_lds16s(const short* g, short* l) {
  __builtin_amdgcn_global_load_lds(
      (const __attribute__((address_space(1))) unsigned int*)g,
      (__attribute__((address_space(3))) unsigned int*)l, 16, 0, 0);
}

__device__ __forceinline__ unsigned bf16rne(float v) {
  unsigned u = __float_as_uint(v);
  return (u + 0x7FFFu + ((u >> 16) & 1u)) >> 16;
}

// ============ prep_x: X fp32 [M][K] -> Xh, Xl bf16 in A-frag panel order =====
// panel = (row/16)*(K/32) + k/32 ; within panel: lane l = (row%16)+((k%32)/8)*16,
// j = k%8 ; linear offset = (panel*64 + l)*8 + j. Xl holds (X - Xh)*256.
__global__ __launch_bounds__(256) void prep_x(
    const float* __restrict__ X, short* __restrict__ Xh, short* __restrict__ Xl,
    int K) {
  __shared__ float plds[16 * 132];
  const int t = threadIdx.x;
  const int blk = blockIdx.x;            // 16 rows per block; M divisible by 16
  const int LW = K + 4;
  for (int i = t * 4; i < 16 * K; i += 1024) {
    int r = i / K, k = i - r * K;
    *(float4*)&plds[r * LW + k] = *(const float4*)&X[(size_t)(blk * 16 + r) * K + k];
  }
  __syncthreads();
  for (int c = t; c < 2 * K; c += 256) {  // chunks: panel p_k = c>>6, lane = c&63
    int p_k = c >> 6, l = c & 63;
    int r = l & 15, k0 = p_k * 32 + (l >> 4) * 8;
    unsigned hp[4], lp[4];
#pragma unroll
    for (int q = 0; q < 4; ++q) {
      float v0 = plds[r * LW + k0 + q * 2];
      float v1 = plds[r * LW + k0 + q * 2 + 1];
      unsigned h0 = bf16rne(v0), h1 = bf16rne(v1);
      float l0 = (v0 - __uint_as_float(h0 << 16)) * 256.0f;
      float l1 = (v1 - __uint_as_float(h1 << 16)) * 256.0f;
      hp[q] = h0 | (h1 << 16);
      lp[q] = bf16rne(l0) | (bf16rne(l1) << 16);
    }
    size_t base = ((size_t)(blk * (K >> 5) + p_k) * 64 + l) * 8;
    *(int4*)&Xh[base] = make_int4(hp[0], hp[1], hp[2], hp[3]);
    *(int4*)&Xl[base] = make_int4(lp[0], lp[1], lp[2], lp[3]);
  }
}

// ============ prep_w: W fp32 [K][256] -> Wh, Wl bf16 in B-frag panel order ====
// panel = (col/16)*(K/32) + k/32 ; lane l = (col%16)+((k%32)/8)*16 ; j = k%8.
__global__ __launch_bounds__(256) void prep_w(
    const float* __restrict__ W, short* __restrict__ Wh, short* __restrict__ Wl,
    int K) {
  const int c = blockIdx.x * 256 + threadIdx.x;
  const int KP = K >> 5;
  if (c >= 16 * KP * 64) return;
  const int p = c >> 6, l = c & 63;
  const int p_c = p / KP, p_k = p - p_c * KP;
  const int col = p_c * 16 + (l & 15), k0 = p_k * 32 + (l >> 4) * 8;
  unsigned hp[4], lp[4];
#pragma unroll
  for (int q = 0; q < 4; ++q) {
    float v0 = W[(size_t)(k0 + q * 2) * HC + col];
    float v1 = W[(size_t)(k0 + q * 2 + 1) * HC + col];
    unsigned h0 = bf16rne(v0), h1 = bf16rne(v1);
    float l0 = (v0 - __uint_as_float(h0 << 16)) * 256.0f;
    float l1 = (v1 - __uint_as_float(h1 << 16)) * 256.0f;
    hp[q] = h0 | (h1 << 16);
    lp[q] = bf16rne(l0) | (bf16rne(l1) << 16);
  }
  size_t base = (size_t)c * 8;
  *(int4*)&Wh[base] = make_int4(hp[0], hp[1], hp[2], hp[3]);
  *(int4*)&Wl[base] = make_int4(lp[0], lp[1], lp[2], lp[3]);
}

// ============ MFMA GEMM + fused alpha: 64 rows x 128 cols per block ==========
// Split-bf16: xs = Xh@Wh + (Xh@Wl + Xl@Wh)/256. 4 waves; wave w = rows
// [w*16,w*16+16) x 128 cols = 8 MFMA tiles x {acc0,acc1}. Staging: 24 panels
// (1KB each) per k-step via global_load_lds (6/wave, counted vmcnt(6), dbuf).
// Frag reads are consecutive ds_read_b128 (panel order) -> conflict-free.
__global__ __launch_bounds__(256, 4) void gemm_mfma(
    const short* __restrict__ Xh, const short* __restrict__ Xl,
    const short* __restrict__ Wh, const short* __restrict__ Wl,
    const float* __restrict__ a_s, const float* __restrict__ a_d,
    __half2* __restrict__ xs16, float* __restrict__ asrc, float* __restrict__ adst,
    int M, int K) {
  __shared__ short lds[2][24 * 512];     // 24KB per buf: [Xh4|Xl4|Wh8|Wl8]
  const int t = threadIdx.x;
  const int wv = t >> 6, l = t & 63;
  const int KP = K >> 5;
  const int pr0 = blockIdx.x * 4;        // row-panel base (64 rows)
  const int pc0 = blockIdx.y * 8;        // col-panel base (128 cols)
  const int c0 = blockIdx.y * 128;

#define STAGE(BI, PK)                                                         \
  {                                                                           \
    _Pragma("unroll")                                                         \
    for (int j = 0; j < 6; ++j) {                                             \
      const int s = wv * 6 + j;                                               \
      const short* srcp;                                                      \
      if (s < 4)       srcp = Xh + (((size_t)(pr0 + s) * KP + (PK)) << 9);    \
      else if (s < 8)  srcp = Xl + (((size_t)(pr0 + s - 4) * KP + (PK)) << 9);\
      else if (s < 16) srcp = Wh + (((size_t)(pc0 + s - 8) * KP + (PK)) << 9);\
      else             srcp = Wl + (((size_t)(pc0 + s - 16) * KP + (PK)) << 9);\
      load_lds16s(srcp + l * 8, &lds[BI][s * 512]);                           \
    }                                                                         \
  }

  f32x4 acc0[8], acc1[8];
#pragma unroll
  for (int i = 0; i < 8; ++i)
#pragma unroll
    for (int c = 0; c < 4; ++c) { acc0[i][c] = 0.f; acc1[i][c] = 0.f; }

  STAGE(0, 0);
  for (int pk = 0; pk < KP; ++pk) {
    const int cur = pk & 1;
    if (pk + 1 < KP) {
      STAGE(cur ^ 1, pk + 1);
      asm volatile("s_waitcnt vmcnt(6)" ::: "memory");
    } else {
      asm volatile("s_waitcnt vmcnt(0)" ::: "memory");
    }
    __builtin_amdgcn_s_barrier();
    __builtin_amdgcn_sched_barrier(0);
    const short8 ah = *(const short8*)&lds[cur][(0 + wv) * 512 + l * 8];
    const short8 al = *(const short8*)&lds[cur][(4 + wv) * 512 + l * 8];
#pragma unroll
    for (int t8 = 0; t8 < 8; ++t8) {
      const short8 bh = *(const short8*)&lds[cur][(8 + t8) * 512 + l * 8];
      const short8 bl = *(const short8*)&lds[cur][(16 + t8) * 512 + l * 8];
      acc0[t8] = __builtin_amdgcn_mfma_f32_16x16x32_bf16(ah, bh, acc0[t8], 0, 0, 0);
      acc1[t8] = __builtin_amdgcn_mfma_f32_16x16x32_bf16(ah, bl, acc1[t8], 0, 0, 0);
      acc1[t8] = __builtin_amdgcn_mfma_f32_16x16x32_bf16(al, bh, acc1[t8], 0, 0, 0);
    }
    asm volatile("" ::: "memory");
    __builtin_amdgcn_s_barrier();
  }
#undef STAGE

  // epilogue: C/D layout col=lane&15, row=(lane>>4)*4+reg (m89-verified)
  const int col_l = l & 15;
  const int row_l = (l >> 4) * 2 * 2;    // (l>>4)*4
  __half* xsh = (__half*)xs16;
  float asv[8], adv[8];
#pragma unroll
  for (int t8 = 0; t8 < 8; ++t8) {
    asv[t8] = a_s[c0 + t8 * 16 + col_l];
    adv[t8] = a_d[c0 + t8 * 16 + col_l];
  }
  float sp[2][4], dp[2][4];
#pragma unroll
  for (int hl = 0; hl < 2; ++hl)
#pragma unroll
    for (int r = 0; r < 4; ++r) { sp[hl][r] = 0.f; dp[hl][r] = 0.f; }

#pragma unroll
  for (int t8 = 0; t8 < 8; ++t8) {
    const int hl = t8 >> 2;
#pragma unroll
    for (int r = 0; r < 4; ++r) {
      const float v = acc0[t8][r] + acc1[t8][r] * (1.0f / 256.0f);
      const int row = (pr0 + wv) * 16 + row_l + r;
      if (row < M) {
        const int col = c0 + t8 * 16 + col_l;
        xsh[(size_t)row * HC + col] = __float2half(v);
      }
      sp[hl][r] += v * asv[t8];
      dp[hl][r] += v * adv[t8];
    }
  }
#pragma unroll
  for (int off = 1; off < 16; off <<= 1) {
#pragma unroll
    for (int hl = 0; hl < 2; ++hl)
#pragma unroll
      for (int r = 0; r < 4; ++r) {
        sp[hl][r] += __shfl_xor(sp[hl][r], off);
        dp[hl][r] += __shfl_xor(dp[hl][r], off);
      }
  }
  if (col_l == 0) {
#pragma unroll
    for (int hl = 0; hl < 2; ++hl) {
      const int head = blockIdx.y * 2 + hl;
#pragma unroll
      for (int r = 0; r < 4; ++r) {
        const int row = (pr0 + wv) * 16 + row_l + r;
        if (row < M) {
          asrc[row * NHEAD + head] = sp[hl][r];
          adst[row * NHEAD + head] = dp[hl][r];
        }
      }
    }
  }
}

// ============ per-relation alpha_e tables for BOTH layers ============
__global__ __launch_bounds__(256) void relalpha2_kernel(
    const float* __restrict__ rel1, const float* __restrict__ We1, const float* __restrict__ ae1,
    const float* __restrict__ rel2, const float* __restrict__ We2, const float* __restrict__ ae2,
    float* __restrict__ tab1, float* __restrict__ tab2) {
  const int layer = blockIdx.x >> 6;
  const int r = blockIdx.x & 63;
  const float* rel = layer ? rel2 : rel1;
  const float* We  = layer ? We2  : We1;
  const float* ae  = layer ? ae2  : ae1;
  float* tab       = layer ? tab2 : tab1;
  const int K      = layer ? 64   : IN_DIM;
  int t = threadIdx.x;
  float acc = 0.f;
  for (int k = 0; k < K; ++k) acc += rel[(size_t)r * K + k] * We[(size_t)k * HC + t];
  int h = t >> 6, lane = t & 63;
  float p = acc * ae[t];
#pragma unroll
  for (int off = 32; off > 0; off >>= 1) p += __shfl_down(p, off);
  if (lane == 0) tab[r * NHEAD + h] = p;
}

// ============ CSR build ============
__global__ __launch_bounds__(256) void hist_kernel(
    const int* __restrict__ dst, int* __restrict__ deg) {
  int e = blockIdx.x * blockDim.x + threadIdx.x;
  if (e < N_EDGES) atomicAdd(&deg[dst[e]], 1);
}

__global__ __launch_bounds__(256) void block_sum_kernel(
    const int* __restrict__ deg, int* __restrict__ bsum) {
  int i = blockIdx.x * 256 + threadIdx.x;
  int v = (i < N_NODES) ? deg[i] : 0;
#pragma unroll
  for (int off = 32; off > 0; off >>= 1) v += __shfl_down(v, off);
  __shared__ int w[4];
  if ((threadIdx.x & 63) == 0) w[threadIdx.x >> 6] = v;
  __syncthreads();
  if (threadIdx.x == 0) bsum[blockIdx.x] = w[0] + w[1] + w[2] + w[3];
}

__global__ __launch_bounds__(256) void scan_bsum_kernel(
    const int* __restrict__ bsum, int* __restrict__ boff) {
  __shared__ int s[256];
  int t = threadIdx.x;
  int v = (t < SCAN_B) ? bsum[t] : 0;
  s[t] = v;
  __syncthreads();
  for (int off = 1; off < 256; off <<= 1) {
    int u = (t >= off) ? s[t - off] : 0;
    __syncthreads();
    s[t] += u;
    __syncthreads();
  }
  boff[t] = (t == 0) ? 0 : s[t - 1];
}

__global__ __launch_bounds__(256) void scan_final_kernel(
    const int* __restrict__ deg, const int* __restrict__ boff,
    int* __restrict__ rowptr, int* __restrict__ cursor) {
  __shared__ int s[256];
  int t = threadIdx.x;
  int i = blockIdx.x * 256 + t;
  int v = (i < N_NODES) ? deg[i] : 0;
  s[t] = v;
  __syncthreads();
  for (int off = 1; off < 256; off <<= 1) {
    int u = (t >= off) ? s[t - off] : 0;
    __syncthreads();
    s[t] += u;
    __syncthreads();
  }
  int excl = boff[blockIdx.x] + s[t] - v;
  if (i < N_NODES) {
    rowptr[i] = excl;
    cursor[i] = excl;
  }
  if (t == 0 && blockIdx.x == 0) rowptr[N_NODES] = N_EDGES;
}

__global__ __launch_bounds__(256) void fill_kernel(
    const int* __restrict__ src, const int* __restrict__ dst,
    const int* __restrict__ etype, int* __restrict__ cursor,
    int2* __restrict__ csr_pack) {
  int e = blockIdx.x * blockDim.x + threadIdx.x;
  if (e >= N_EDGES) return;
  int d = dst[e];
  int i = atomicAdd(&cursor[d], 1);
  csr_pack[i] = make_int2(src[e], etype[e]);
}

// ============ fused no-max softmax + fp16 gather: ONE WAVE PER NODE ============
__global__ __launch_bounds__(256) void gat_node_kernel(
    const int* __restrict__ rowptr, const int2* __restrict__ csr,
    const float* __restrict__ asrc, const float* __restrict__ adst,
    const float* __restrict__ tab, const __half2* __restrict__ xs16,
    const float* __restrict__ b, float* __restrict__ out, int relu) {
  const int n = (blockIdx.x * blockDim.x + threadIdx.x) >> 6;
  if (n >= N_NODES) return;
  const int lane = threadIdx.x & 63;
  const int hh = lane >> 4;               // head of this lane's 4 cols
  const int cbase = lane << 2;
  const int i0 = rowptr[n], i1 = rowptr[n + 1];
  const float adn = adst[n * NHEAD + hh];
  const float treg = tab[lane * NHEAD + hh];   // lane = rel id (NREL==64)

  float4 acc = make_float4(0.f, 0.f, 0.f, 0.f);
  float den = 0.f;
  int i = i0;
  for (; i + 4 <= i1; i += 4) {
    const int2 p0 = csr[i], p1 = csr[i + 1], p2 = csr[i + 2], p3 = csr[i + 3];
    float l0 = asrc[p0.x * NHEAD + hh] + adn + __shfl(treg, p0.y);
    float l1 = asrc[p1.x * NHEAD + hh] + adn + __shfl(treg, p1.y);
    float l2 = asrc[p2.x * NHEAD + hh] + adn + __shfl(treg, p2.y);
    float l3 = asrc[p3.x * NHEAD + hh] + adn + __shfl(treg, p3.y);
    const uint2 q0 = *(const uint2*)&xs16[((size_t)p0.x * HC + cbase) >> 1];
    const uint2 q1 = *(const uint2*)&xs16[((size_t)p1.x * HC + cbase) >> 1];
    const uint2 q2 = *(const uint2*)&xs16[((size_t)p2.x * HC + cbase) >> 1];
    const uint2 q3 = *(const uint2*)&xs16[((size_t)p3.x * HC + cbase) >> 1];
    l0 = (l0 >= 0.f) ? l0 : NEG_SLOPE * l0;
    l1 = (l1 >= 0.f) ? l1 : NEG_SLOPE * l1;
    l2 = (l2 >= 0.f) ? l2 : NEG_SLOPE * l2;
    l3 = (l3 >= 0.f) ? l3 : NEG_SLOPE * l3;
    const float w0 = __expf(l0), w1 = __expf(l1), w2 = __expf(l2), w3 = __expf(l3);
    den += (w0 + w1) + (w2 + w3);
    const float2 a0 = __half22float2(*(const __half2*)&q0.x), b0 = __half22float2(*(const __half2*)&q0.y);
    const float2 a1 = __half22float2(*(const __half2*)&q1.x), b1 = __half22float2(*(const __half2*)&q1.y);
    const float2 a2 = __half22float2(*(const __half2*)&q2.x), b2 = __half22float2(*(const __half2*)&q2.y);
    const float2 a3 = __half22float2(*(const __half2*)&q3.x), b3 = __half22float2(*(const __half2*)&q3.y);
    acc.x += w0 * a0.x + w1 * a1.x + w2 * a2.x + w3 * a3.x;
    acc.y += w0 * a0.y + w1 * a1.y + w2 * a2.y + w3 * a3.y;
    acc.z += w0 * b0.x + w1 * b1.x + w2 * b2.x + w3 * b3.x;
    acc.w += w0 * b0.y + w1 * b1.y + w2 * b2.y + w3 * b3.y;
  }
  for (; i < i1; ++i) {
    const int2 p = csr[i];
    float l = asrc[p.x * NHEAD + hh] + adn + __shfl(treg, p.y);
    l = (l >= 0.f) ? l : NEG_SLOPE * l;
    const float w = __expf(l);
    const uint2 q = *(const uint2*)&xs16[((size_t)p.x * HC + cbase) >> 1];
    const float2 a = __half22float2(*(const __half2*)&q.x);
    const float2 c = __half22float2(*(const __half2*)&q.y);
    den += w;
    acc.x += w * a.x; acc.y += w * a.y; acc.z += w * c.x; acc.w += w * c.y;
  }

  const float rd = (den > 0.f) ? (0.25f / den) : 0.f;
  float4 y = make_float4(acc.x * rd, acc.y * rd, acc.z * rd, acc.w * rd);
#pragma unroll
  for (int off = 16; off < 64; off <<= 1) {
    y.x += __shfl_xor(y.x, off);
    y.y += __shfl_xor(y.y, off);
    y.z += __shfl_xor(y.z, off);
    y.w += __shfl_xor(y.w, off);
  }
  if (lane < 16) {
    const float4 bb = *(const float4*)&b[lane * 4];
    y.x += bb.x; y.y += bb.y; y.z += bb.z; y.w += bb.w;
    if (relu) {
      y.x = fmaxf(y.x, 0.f); y.y = fmaxf(y.y, 0.f);
      y.z = fmaxf(y.z, 0.f); y.w = fmaxf(y.w, 0.f);
    }
    *(float4*)&out[(size_t)n * 64 + lane * 4] = y;
  }
}

extern "C" void kernel_launch(void* const* d_in, const int* in_sizes, int n_in,
                              void* d_out, int out_size, void* d_ws, size_t ws_size,
                              hipStream_t stream) {
  const float* x   = (const float*)d_in[0];
  const int* eidx  = (const int*)d_in[1];
  const int* etype = (const int*)d_in[2];
  const float* rel1 = (const float*)d_in[3];
  const float* W1   = (const float*)d_in[4];
  const float* We1  = (const float*)d_in[5];
  const float* as1  = (const float*)d_in[6];
  const float* ad1  = (const float*)d_in[7];
  const float* ae1  = (const float*)d_in[8];
  const float* b1   = (const float*)d_in[9];
  const float* rel2 = (const float*)d_in[10];
  const float* W2   = (const float*)d_in[11];
  const float* We2  = (const float*)d_in[12];
  const float* as2  = (const float*)d_in[13];
  const float* ad2  = (const float*)d_in[14];
  const float* ae2  = (const float*)d_in[15];
  const float* b2   = (const float*)d_in[16];
  const int* src = eidx;
  const int* dst = eidx + N_EDGES;

  // ---- workspace layout (byte offsets, 256B-aligned regions) ----
  char* wsb = (char*)d_ws;
  size_t off = 0;
  auto carve = [&](size_t bytes) { char* p = wsb + off; off = (off + bytes + 255) & ~(size_t)255; return p; };
  __half2* xs16 = (__half2*)carve((size_t)N_NODES * HC * 2);          // 25.6MB
  float* asrc = (float*)carve((size_t)N_NODES * NHEAD * 4);
  float* adst = (float*)carve((size_t)N_NODES * NHEAD * 4);
  float* tab1 = (float*)carve(NREL * NHEAD * 4);
  float* tab2 = (float*)carve(NREL * NHEAD * 4);
  float* h1   = (float*)carve((size_t)N_NODES * 64 * 4);              // 12.8MB
  short* xfh  = (short*)carve(((size_t)N_NODES * IN_DIM + 32768) * 2);// 12.9MB
  short* xfl  = (short*)carve(((size_t)N_NODES * IN_DIM + 32768) * 2);
  short* w1h  = (short*)carve(256 * IN_DIM * 2);
  short* w1l  = (short*)carve(256 * IN_DIM * 2);
  short* w2h  = (short*)carve(256 * 64 * 2);
  short* w2l  = (short*)carve(256 * 64 * 2);
  int* deg    = (int*)carve(N_NODES * 4);
  int* rowptr = (int*)carve((N_NODES + 1) * 4);
  int* cursor = (int*)carve(N_NODES * 4);
  int2* csr   = (int2*)carve((size_t)N_EDGES * 8);
  int* bsum   = (int*)carve(256 * 4);
  int* boff   = (int*)carve(256 * 4);

  // ---- CSR build + alpha_e tables + weight/feature split preps ----
  hipMemsetAsync(deg, 0, N_NODES * sizeof(int), stream);
  hist_kernel<<<(N_EDGES + 255) / 256, 256, 0, stream>>>(dst, deg);
  block_sum_kernel<<<SCAN_B, 256, 0, stream>>>(deg, bsum);
  scan_bsum_kernel<<<1, 256, 0, stream>>>(bsum, boff);
  scan_final_kernel<<<SCAN_B, 256, 0, stream>>>(deg, boff, rowptr, cursor);
  fill_kernel<<<(N_EDGES + 255) / 256, 256, 0, stream>>>(src, dst, etype, cursor, csr);
  relalpha2_kernel<<<2 * NREL, 256, 0, stream>>>(rel1, We1, ae1, rel2, We2, ae2, tab1, tab2);
  prep_w<<<(16 * (IN_DIM >> 5) * 64 + 255) / 256, 256, 0, stream>>>(W1, w1h, w1l, IN_DIM);
  prep_w<<<(16 * (64 >> 5) * 64 + 255) / 256, 256, 0, stream>>>(W2, w2h, w2l, 64);

  const dim3 gemm_grid((N_NODES + 63) / 64, 2);
  const int GB = (N_NODES * 64 + 255) / 256;   // one wave per node
  const int XB = N_NODES / 16;                 // 3125 (N divisible by 16)

  // ================= layer 1 =================
  prep_x<<<XB, 256, 0, stream>>>(x, xfh, xfl, IN_DIM);
  gemm_mfma<<<gemm_grid, 256, 0, stream>>>(xfh, xfl, w1h, w1l, as1, ad1, xs16, asrc, adst, N_NODES, IN_DIM);
  gat_node_kernel<<<GB, 256, 0, stream>>>(rowptr, csr, asrc, adst, tab1, xs16, b1, h1, 1);

  // ================= layer 2 =================
  prep_x<<<XB, 256, 0, stream>>>(h1, xfh, xfl, 64);
  gemm_mfma<<<gemm_grid, 256, 0, stream>>>(xfh, xfl, w2h, w2l, as2, ad2, xs16, asrc, adst, N_NODES, 64);
  gat_node_kernel<<<GB, 256, 0, stream>>>(rowptr, csr, asrc, adst, tab2, xs16, b2, (float*)d_out, 0);
}

// Round 16
// 309.519 us; speedup vs baseline: 1.3728x; 1.0294x over previous
//
#include <hip/hip_runtime.h>
#include <hip/hip_bf16.h>
#include <hip/hip_fp16.h>
#include <math.h>

#define N_NODES 50000
#define N_EDGES 800000
#define IN_DIM 128
#define NHEAD 4
#define NREL 64
#define HC 256              // NHEAD * 64 (both layers: H*HID = H*OUT = 256)
#define NEG_SLOPE 0.2f
#define SCAN_B ((N_NODES + 255) / 256)   // 196 blocks
#define XB (N_NODES / 16)                // 3125 prep_x blocks
#define HB ((N_EDGES + 255) / 256)       // 3125 hist/fill blocks
#define GEMM_BLKS (((N_NODES + 63) / 64) * 2)   // 1564

using short8 = __attribute__((ext_vector_type(8))) short;   // 8 bf16 (4 VGPRs)
using f32x4  = __attribute__((ext_vector_type(4))) float;

// async global->LDS, 16B per lane (zero VGPR staging)
__device__ __forceinline__ void load_lds16s(const short* g, short* l) {
  __builtin_amdgcn_global_load_lds(
      (const __attribute__((address_space(1))) unsigned int*)g,
      (__attribute__((address_space(3))) unsigned int*)l, 16, 0, 0);
}

__device__ __forceinline__ unsigned bf16rne(float v) {
  unsigned u = __float_as_uint(v);
  return (u + 0x7FFFu + ((u >> 16) & 1u)) >> 16;
}

// ============ fused prep: prep_x(l1) | hist | relalpha(x2) | prep_w(x2) ======
// All regions independent; branch by blockIdx region. prep_x emits A-frag
// panel order: panel=(row/16)*(K/32)+k/32; lane=(row%16)+((k%32)/8)*16; j=k%8.
__global__ __launch_bounds__(256) void fused_prep(
    const float* __restrict__ x, short* __restrict__ xfh, short* __restrict__ xfl,
    const int* __restrict__ dst, int* __restrict__ deg,
    const float* __restrict__ rel1, const float* __restrict__ We1, const float* __restrict__ ae1,
    const float* __restrict__ rel2, const float* __restrict__ We2, const float* __restrict__ ae2,
    float* __restrict__ tab1, float* __restrict__ tab2,
    const float* __restrict__ W1, short* __restrict__ w1h, short* __restrict__ w1l,
    const float* __restrict__ W2, short* __restrict__ w2h, short* __restrict__ w2l) {
  const int bid = blockIdx.x;
  const int t = threadIdx.x;
  __shared__ float plds[16 * 132];

  if (bid < XB) {
    // ---- prep_x for layer-1 input (K = IN_DIM = 128) ----
    const int K = IN_DIM, LW = K + 4;
    for (int i = t * 4; i < 16 * K; i += 1024) {
      int r = i / K, k = i - r * K;
      *(float4*)&plds[r * LW + k] = *(const float4*)&x[(size_t)(bid * 16 + r) * K + k];
    }
    __syncthreads();
    for (int c = t; c < 2 * K; c += 256) {
      int p_k = c >> 6, l = c & 63;
      int r = l & 15, k0 = p_k * 32 + (l >> 4) * 8;
      unsigned hp[4], lp[4];
#pragma unroll
      for (int q = 0; q < 4; ++q) {
        float v0 = plds[r * LW + k0 + q * 2];
        float v1 = plds[r * LW + k0 + q * 2 + 1];
        unsigned h0 = bf16rne(v0), h1 = bf16rne(v1);
        float l0 = (v0 - __uint_as_float(h0 << 16)) * 256.0f;
        float l1 = (v1 - __uint_as_float(h1 << 16)) * 256.0f;
        hp[q] = h0 | (h1 << 16);
        lp[q] = bf16rne(l0) | (bf16rne(l1) << 16);
      }
      size_t base = ((size_t)(bid * (K >> 5) + p_k) * 64 + l) * 8;
      *(int4*)&xfh[base] = make_int4(hp[0], hp[1], hp[2], hp[3]);
      *(int4*)&xfl[base] = make_int4(lp[0], lp[1], lp[2], lp[3]);
    }
    return;
  }
  if (bid < XB + HB) {
    // ---- hist ----
    const int e = (bid - XB) * 256 + t;
    if (e < N_EDGES) atomicAdd(&deg[dst[e]], 1);
    return;
  }
  if (bid < XB + HB + 128) {
    // ---- relalpha, both layers ----
    const int rb = bid - (XB + HB);
    const int layer = rb >> 6, r = rb & 63;
    const float* rel = layer ? rel2 : rel1;
    const float* We  = layer ? We2  : We1;
    const float* ae  = layer ? ae2  : ae1;
    float* tab       = layer ? tab2 : tab1;
    const int K      = layer ? 64   : IN_DIM;
    float acc = 0.f;
    for (int k = 0; k < K; ++k) acc += rel[(size_t)r * K + k] * We[(size_t)k * HC + t];
    int h = t >> 6, lane = t & 63;
    float p = acc * ae[t];
#pragma unroll
    for (int off = 32; off > 0; off >>= 1) p += __shfl_down(p, off);
    if (lane == 0) tab[r * NHEAD + h] = p;
    return;
  }
  {
    // ---- prep_w (W1: 16 blocks, W2: 8 blocks) ----
    const int wb = bid - (XB + HB + 128);
    const float* W; short* Wh; short* Wl; int K, c;
    if (wb < 16) { W = W1; Wh = w1h; Wl = w1l; K = IN_DIM; c = wb * 256 + t; }
    else         { W = W2; Wh = w2h; Wl = w2l; K = 64;     c = (wb - 16) * 256 + t; }
    const int KP = K >> 5;
    if (c >= 16 * KP * 64) return;
    const int p = c >> 6, l = c & 63;
    const int p_c = p / KP, p_k = p - p_c * KP;
    const int col = p_c * 16 + (l & 15), k0 = p_k * 32 + (l >> 4) * 8;
    unsigned hp[4], lp[4];
#pragma unroll
    for (int q = 0; q < 4; ++q) {
      float v0 = W[(size_t)(k0 + q * 2) * HC + col];
      float v1 = W[(size_t)(k0 + q * 2 + 1) * HC + col];
      unsigned h0 = bf16rne(v0), h1 = bf16rne(v1);
      float l0 = (v0 - __uint_as_float(h0 << 16)) * 256.0f;
      float l1 = (v1 - __uint_as_float(h1 << 16)) * 256.0f;
      hp[q] = h0 | (h1 << 16);
      lp[q] = bf16rne(l0) | (bf16rne(l1) << 16);
    }
    size_t base = (size_t)c * 8;
    *(int4*)&Wh[base] = make_int4(hp[0], hp[1], hp[2], hp[3]);
    *(int4*)&Wl[base] = make_int4(lp[0], lp[1], lp[2], lp[3]);
  }
}

// ============ MFMA GEMM (+ appended CSR-fill blocks for layer 1) =============
// Split-bf16: xs = Xh@Wh + (Xh@Wl + Xl@Wh)/256. R15-proven structure; 1D grid:
// bid<GEMM_BLKS -> gemm (row-panel bid>>1, col-half bid&1); else fill block.
__global__ __launch_bounds__(256, 4) void gemm_fill(
    const short* __restrict__ Xh, const short* __restrict__ Xl,
    const short* __restrict__ Wh, const short* __restrict__ Wl,
    const float* __restrict__ a_s, const float* __restrict__ a_d,
    __half2* __restrict__ xs16, float* __restrict__ asrc, float* __restrict__ adst,
    int M, int K,
    const int* __restrict__ src, const int* __restrict__ dstv,
    const int* __restrict__ etype, int* __restrict__ cursor,
    int2* __restrict__ csr) {
  __shared__ short lds[2][24 * 512];     // 24KB per buf: [Xh4|Xl4|Wh8|Wl8]
  const int bid = blockIdx.x;
  const int t = threadIdx.x;
  if (bid >= GEMM_BLKS) {
    // ---- CSR fill (overlaps with gemm on layer 1) ----
    const int e = (bid - GEMM_BLKS) * 256 + t;
    if (e < N_EDGES) {
      const int d = dstv[e];
      const int i = atomicAdd(&cursor[d], 1);
      csr[i] = make_int2(src[e], etype[e]);
    }
    return;
  }
  const int wv = t >> 6, l = t & 63;
  const int KP = K >> 5;
  const int pr0 = (bid >> 1) * 4;        // row-panel base (64 rows)
  const int pc0 = (bid & 1) * 8;         // col-panel base (128 cols)
  const int c0 = (bid & 1) * 128;

#define STAGE(BI, PK)                                                         \
  {                                                                           \
    _Pragma("unroll")                                                         \
    for (int j = 0; j < 6; ++j) {                                             \
      const int s = wv * 6 + j;                                               \
      const short* srcp;                                                      \
      if (s < 4)       srcp = Xh + (((size_t)(pr0 + s) * KP + (PK)) << 9);    \
      else if (s < 8)  srcp = Xl + (((size_t)(pr0 + s - 4) * KP + (PK)) << 9);\
      else if (s < 16) srcp = Wh + (((size_t)(pc0 + s - 8) * KP + (PK)) << 9);\
      else             srcp = Wl + (((size_t)(pc0 + s - 16) * KP + (PK)) << 9);\
      load_lds16s(srcp + l * 8, &lds[BI][s * 512]);                           \
    }                                                                         \
  }

  f32x4 acc0[8], acc1[8];
#pragma unroll
  for (int i = 0; i < 8; ++i)
#pragma unroll
    for (int c = 0; c < 4; ++c) { acc0[i][c] = 0.f; acc1[i][c] = 0.f; }

  STAGE(0, 0);
  for (int pk = 0; pk < KP; ++pk) {
    const int cur = pk & 1;
    if (pk + 1 < KP) {
      STAGE(cur ^ 1, pk + 1);
      asm volatile("s_waitcnt vmcnt(6)" ::: "memory");
    } else {
      asm volatile("s_waitcnt vmcnt(0)" ::: "memory");
    }
    __builtin_amdgcn_s_barrier();
    __builtin_amdgcn_sched_barrier(0);
    const short8 ah = *(const short8*)&lds[cur][(0 + wv) * 512 + l * 8];
    const short8 al = *(const short8*)&lds[cur][(4 + wv) * 512 + l * 8];
#pragma unroll
    for (int t8 = 0; t8 < 8; ++t8) {
      const short8 bh = *(const short8*)&lds[cur][(8 + t8) * 512 + l * 8];
      const short8 bl = *(const short8*)&lds[cur][(16 + t8) * 512 + l * 8];
      acc0[t8] = __builtin_amdgcn_mfma_f32_16x16x32_bf16(ah, bh, acc0[t8], 0, 0, 0);
      acc1[t8] = __builtin_amdgcn_mfma_f32_16x16x32_bf16(ah, bl, acc1[t8], 0, 0, 0);
      acc1[t8] = __builtin_amdgcn_mfma_f32_16x16x32_bf16(al, bh, acc1[t8], 0, 0, 0);
    }
    asm volatile("" ::: "memory");
    __builtin_amdgcn_s_barrier();
  }
#undef STAGE

  // epilogue: C/D layout col=lane&15, row=(lane>>4)*4+reg (m89-verified)
  const int col_l = l & 15;
  const int row_l = (l >> 4) * 4;
  __half* xsh = (__half*)xs16;
  float asv[8], adv[8];
#pragma unroll
  for (int t8 = 0; t8 < 8; ++t8) {
    asv[t8] = a_s[c0 + t8 * 16 + col_l];
    adv[t8] = a_d[c0 + t8 * 16 + col_l];
  }
  float sp[2][4], dp[2][4];
#pragma unroll
  for (int hl = 0; hl < 2; ++hl)
#pragma unroll
    for (int r = 0; r < 4; ++r) { sp[hl][r] = 0.f; dp[hl][r] = 0.f; }

#pragma unroll
  for (int t8 = 0; t8 < 8; ++t8) {
    const int hl = t8 >> 2;
#pragma unroll
    for (int r = 0; r < 4; ++r) {
      const float v = acc0[t8][r] + acc1[t8][r] * (1.0f / 256.0f);
      const int row = (pr0 + wv) * 16 + row_l + r;
      if (row < M) {
        const int col = c0 + t8 * 16 + col_l;
        xsh[(size_t)row * HC + col] = __float2half(v);
      }
      sp[hl][r] += v * asv[t8];
      dp[hl][r] += v * adv[t8];
    }
  }
#pragma unroll
  for (int off = 1; off < 16; off <<= 1) {
#pragma unroll
    for (int hl = 0; hl < 2; ++hl)
#pragma unroll
      for (int r = 0; r < 4; ++r) {
        sp[hl][r] += __shfl_xor(sp[hl][r], off);
        dp[hl][r] += __shfl_xor(dp[hl][r], off);
      }
  }
  if (col_l == 0) {
#pragma unroll
    for (int hl = 0; hl < 2; ++hl) {
      const int head = (bid & 1) * 2 + hl;
#pragma unroll
      for (int r = 0; r < 4; ++r) {
        const int row = (pr0 + wv) * 16 + row_l + r;
        if (row < M) {
          asrc[row * NHEAD + head] = sp[hl][r];
          adst[row * NHEAD + head] = dp[hl][r];
        }
      }
    }
  }
}

// ============ CSR scan chain ============
__global__ __launch_bounds__(256) void block_sum_kernel(
    const int* __restrict__ deg, int* __restrict__ bsum) {
  int i = blockIdx.x * 256 + threadIdx.x;
  int v = (i < N_NODES) ? deg[i] : 0;
#pragma unroll
  for (int off = 32; off > 0; off >>= 1) v += __shfl_down(v, off);
  __shared__ int w[4];
  if ((threadIdx.x & 63) == 0) w[threadIdx.x >> 6] = v;
  __syncthreads();
  if (threadIdx.x == 0) bsum[blockIdx.x] = w[0] + w[1] + w[2] + w[3];
}

__global__ __launch_bounds__(256) void scan_bsum_kernel(
    const int* __restrict__ bsum, int* __restrict__ boff) {
  __shared__ int s[256];
  int t = threadIdx.x;
  int v = (t < SCAN_B) ? bsum[t] : 0;
  s[t] = v;
  __syncthreads();
  for (int off = 1; off < 256; off <<= 1) {
    int u = (t >= off) ? s[t - off] : 0;
    __syncthreads();
    s[t] += u;
    __syncthreads();
  }
  boff[t] = (t == 0) ? 0 : s[t - 1];
}

__global__ __launch_bounds__(256) void scan_final_kernel(
    const int* __restrict__ deg, const int* __restrict__ boff,
    int* __restrict__ rowptr, int* __restrict__ cursor) {
  __shared__ int s[256];
  int t = threadIdx.x;
  int i = blockIdx.x * 256 + t;
  int v = (i < N_NODES) ? deg[i] : 0;
  s[t] = v;
  __syncthreads();
  for (int off = 1; off < 256; off <<= 1) {
    int u = (t >= off) ? s[t - off] : 0;
    __syncthreads();
    s[t] += u;
    __syncthreads();
  }
  int excl = boff[blockIdx.x] + s[t] - v;
  if (i < N_NODES) {
    rowptr[i] = excl;
    cursor[i] = excl;
  }
  if (t == 0 && blockIdx.x == 0) rowptr[N_NODES] = N_EDGES;
}

// ============ fused no-max softmax + fp16 gather: ONE WAVE PER NODE ===========
// mode=1 (layer 1): bias+relu, then split-bf16 store in panel order (K=64,
// KP=2) -> feeds gemm layer 2 directly (prep_x l2 eliminated).
// mode=0 (layer 2): bias, fp32 store to out.
__global__ __launch_bounds__(256) void gat_node_kernel(
    const int* __restrict__ rowptr, const int2* __restrict__ csr,
    const float* __restrict__ asrc, const float* __restrict__ adst,
    const float* __restrict__ tab, const __half2* __restrict__ xs16,
    const float* __restrict__ b, float* __restrict__ out,
    short* __restrict__ oxh, short* __restrict__ oxl, int mode) {
  const int n = (blockIdx.x * blockDim.x + threadIdx.x) >> 6;
  if (n >= N_NODES) return;
  const int lane = threadIdx.x & 63;
  const int hh = lane >> 4;               // head of this lane's 4 cols
  const int cbase = lane << 2;
  const int i0 = rowptr[n], i1 = rowptr[n + 1];
  const float adn = adst[n * NHEAD + hh];
  const float treg = tab[lane * NHEAD + hh];   // lane = rel id (NREL==64)

  float4 acc = make_float4(0.f, 0.f, 0.f, 0.f);
  float den = 0.f;
  int i = i0;
  for (; i + 4 <= i1; i += 4) {
    const int2 p0 = csr[i], p1 = csr[i + 1], p2 = csr[i + 2], p3 = csr[i + 3];
    float l0 = asrc[p0.x * NHEAD + hh] + adn + __shfl(treg, p0.y);
    float l1 = asrc[p1.x * NHEAD + hh] + adn + __shfl(treg, p1.y);
    float l2 = asrc[p2.x * NHEAD + hh] + adn + __shfl(treg, p2.y);
    float l3 = asrc[p3.x * NHEAD + hh] + adn + __shfl(treg, p3.y);
    const uint2 q0 = *(const uint2*)&xs16[((size_t)p0.x * HC + cbase) >> 1];
    const uint2 q1 = *(const uint2*)&xs16[((size_t)p1.x * HC + cbase) >> 1];
    const uint2 q2 = *(const uint2*)&xs16[((size_t)p2.x * HC + cbase) >> 1];
    const uint2 q3 = *(const uint2*)&xs16[((size_t)p3.x * HC + cbase) >> 1];
    l0 = (l0 >= 0.f) ? l0 : NEG_SLOPE * l0;
    l1 = (l1 >= 0.f) ? l1 : NEG_SLOPE * l1;
    l2 = (l2 >= 0.f) ? l2 : NEG_SLOPE * l2;
    l3 = (l3 >= 0.f) ? l3 : NEG_SLOPE * l3;
    const float w0 = __expf(l0), w1 = __expf(l1), w2 = __expf(l2), w3 = __expf(l3);
    den += (w0 + w1) + (w2 + w3);
    const float2 a0 = __half22float2(*(const __half2*)&q0.x), b0 = __half22float2(*(const __half2*)&q0.y);
    const float2 a1 = __half22float2(*(const __half2*)&q1.x), b1 = __half22float2(*(const __half2*)&q1.y);
    const float2 a2 = __half22float2(*(const __half2*)&q2.x), b2 = __half22float2(*(const __half2*)&q2.y);
    const float2 a3 = __half22float2(*(const __half2*)&q3.x), b3 = __half22float2(*(const __half2*)&q3.y);
    acc.x += w0 * a0.x + w1 * a1.x + w2 * a2.x + w3 * a3.x;
    acc.y += w0 * a0.y + w1 * a1.y + w2 * a2.y + w3 * a3.y;
    acc.z += w0 * b0.x + w1 * b1.x + w2 * b2.x + w3 * b3.x;
    acc.w += w0 * b0.y + w1 * b1.y + w2 * b2.y + w3 * b3.y;
  }
  for (; i < i1; ++i) {
    const int2 p = csr[i];
    float l = asrc[p.x * NHEAD + hh] + adn + __shfl(treg, p.y);
    l = (l >= 0.f) ? l : NEG_SLOPE * l;
    const float w = __expf(l);
    const uint2 q = *(const uint2*)&xs16[((size_t)p.x * HC + cbase) >> 1];
    const float2 a = __half22float2(*(const __half2*)&q.x);
    const float2 c = __half22float2(*(const __half2*)&q.y);
    den += w;
    acc.x += w * a.x; acc.y += w * a.y; acc.z += w * c.x; acc.w += w * c.y;
  }

  const float rd = (den > 0.f) ? (0.25f / den) : 0.f;
  float4 y = make_float4(acc.x * rd, acc.y * rd, acc.z * rd, acc.w * rd);
#pragma unroll
  for (int off = 16; off < 64; off <<= 1) {
    y.x += __shfl_xor(y.x, off);
    y.y += __shfl_xor(y.y, off);
    y.z += __shfl_xor(y.z, off);
    y.w += __shfl_xor(y.w, off);
  }
  if (lane < 16) {
    const float4 bb = *(const float4*)&b[lane * 4];
    y.x += bb.x; y.y += bb.y; y.z += bb.z; y.w += bb.w;
    if (mode) {
      // relu + split-bf16, panel-order store (verified mapping, K=64)
      y.x = fmaxf(y.x, 0.f); y.y = fmaxf(y.y, 0.f);
      y.z = fmaxf(y.z, 0.f); y.w = fmaxf(y.w, 0.f);
      unsigned h0 = bf16rne(y.x), h1 = bf16rne(y.y);
      unsigned h2 = bf16rne(y.z), h3 = bf16rne(y.w);
      float l0 = (y.x - __uint_as_float(h0 << 16)) * 256.0f;
      float l1 = (y.y - __uint_as_float(h1 << 16)) * 256.0f;
      float l2 = (y.z - __uint_as_float(h2 << 16)) * 256.0f;
      float l3 = (y.w - __uint_as_float(h3 << 16)) * 256.0f;
      unsigned hp0 = h0 | (h1 << 16), hp1 = h2 | (h3 << 16);
      unsigned lp0 = bf16rne(l0) | (bf16rne(l1) << 16);
      unsigned lp1 = bf16rne(l2) | (bf16rne(l3) << 16);
      const int pk = lane >> 3;                       // k0=4*lane; k0/32
      const int lip = (n & 15) + ((lane >> 1) & 3) * 16;
      const int j0 = (lane & 1) * 4;
      size_t base = ((size_t)((n >> 4) * 2 + pk) * 64 + lip) * 8 + j0;
      *(uint2*)&oxh[base] = make_uint2(hp0, hp1);
      *(uint2*)&oxl[base] = make_uint2(lp0, lp1);
    } else {
      *(float4*)&out[(size_t)n * 64 + lane * 4] = y;
    }
  }
}

extern "C" void kernel_launch(void* const* d_in, const int* in_sizes, int n_in,
                              void* d_out, int out_size, void* d_ws, size_t ws_size,
                              hipStream_t stream) {
  const float* x   = (const float*)d_in[0];
  const int* eidx  = (const int*)d_in[1];
  const int* etype = (const int*)d_in[2];
  const float* rel1 = (const float*)d_in[3];
  const float* W1   = (const float*)d_in[4];
  const float* We1  = (const float*)d_in[5];
  const float* as1  = (const float*)d_in[6];
  const float* ad1  = (const float*)d_in[7];
  const float* ae1  = (const float*)d_in[8];
  const float* b1   = (const float*)d_in[9];
  const float* rel2 = (const float*)d_in[10];
  const float* W2   = (const float*)d_in[11];
  const float* We2  = (const float*)d_in[12];
  const float* as2  = (const float*)d_in[13];
  const float* ad2  = (const float*)d_in[14];
  const float* ae2  = (const float*)d_in[15];
  const float* b2   = (const float*)d_in[16];
  const int* src = eidx;
  const int* dst = eidx + N_EDGES;

  // ---- workspace layout (256B-aligned regions) ----
  char* wsb = (char*)d_ws;
  size_t off = 0;
  auto carve = [&](size_t bytes) { char* p = wsb + off; off = (off + bytes + 255) & ~(size_t)255; return p; };
  __half2* xs16 = (__half2*)carve((size_t)N_NODES * HC * 2);          // 25.6MB
  float* asrc = (float*)carve((size_t)N_NODES * NHEAD * 4);
  float* adst = (float*)carve((size_t)N_NODES * NHEAD * 4);
  float* tab1 = (float*)carve(NREL * NHEAD * 4);
  float* tab2 = (float*)carve(NREL * NHEAD * 4);
  short* xfh  = (short*)carve(((size_t)N_NODES * IN_DIM + 32768) * 2);// 12.9MB
  short* xfl  = (short*)carve(((size_t)N_NODES * IN_DIM + 32768) * 2);
  short* w1h  = (short*)carve(256 * IN_DIM * 2);
  short* w1l  = (short*)carve(256 * IN_DIM * 2);
  short* w2h  = (short*)carve(256 * 64 * 2);
  short* w2l  = (short*)carve(256 * 64 * 2);
  int* deg    = (int*)carve(N_NODES * 4);
  int* rowptr = (int*)carve((N_NODES + 1) * 4);
  int* cursor = (int*)carve(N_NODES * 4);
  int2* csr   = (int2*)carve((size_t)N_EDGES * 8);
  int* bsum   = (int*)carve(256 * 4);
  int* boff   = (int*)carve(256 * 4);

  hipMemsetAsync(deg, 0, N_NODES * sizeof(int), stream);

  // fused prep: prep_x(l1) | hist | relalpha x2 | prep_w x2
  fused_prep<<<XB + HB + 128 + 16 + 8, 256, 0, stream>>>(
      x, xfh, xfl, dst, deg,
      rel1, We1, ae1, rel2, We2, ae2, tab1, tab2,
      W1, w1h, w1l, W2, w2h, w2l);

  block_sum_kernel<<<SCAN_B, 256, 0, stream>>>(deg, bsum);
  scan_bsum_kernel<<<1, 256, 0, stream>>>(bsum, boff);
  scan_final_kernel<<<SCAN_B, 256, 0, stream>>>(deg, boff, rowptr, cursor);

  const int GB = (N_NODES * 64 + 255) / 256;   // one wave per node

  // ================= layer 1 (gemm || csr-fill) =================
  gemm_fill<<<GEMM_BLKS + HB, 256, 0, stream>>>(
      xfh, xfl, w1h, w1l, as1, ad1, xs16, asrc, adst, N_NODES, IN_DIM,
      src, dst, etype, cursor, csr);
  gat_node_kernel<<<GB, 256, 0, stream>>>(rowptr, csr, asrc, adst, tab1, xs16,
                                          b1, nullptr, xfh, xfl, 1);

  // ================= layer 2 =================
  gemm_fill<<<GEMM_BLKS, 256, 0, stream>>>(
      xfh, xfl, w2h, w2l, as2, ad2, xs16, asrc, adst, N_NODES, 64,
      src, dst, etype, cursor, csr);
  gat_node_kernel<<<GB, 256, 0, stream>>>(rowptr, csr, asrc, adst, tab2, xs16,
                                          b2, (float*)d_out, nullptr, nullptr, 0);
}

// Round 17
// 302.760 us; speedup vs baseline: 1.4034x; 1.0223x over previous
//
#include <hip/hip_runtime.h>
#include <hip/hip_bf16.h>
#include <hip/hip_fp16.h>
#include <math.h>

#define N_NODES 50000
#define N_EDGES 800000
#define IN_DIM 128
#define NHEAD 4
#define NREL 64
#define HC 256              // NHEAD * 64 (both layers: H*HID = H*OUT = 256)
#define NEG_SLOPE 0.2f
#define SCAN_B ((N_NODES + 255) / 256)   // 196 blocks
#define XB (N_NODES / 16)                // 3125 prep_x blocks
#define HB ((N_EDGES + 255) / 256)       // 3125 hist/fill blocks

using short8 = __attribute__((ext_vector_type(8))) short;   // 8 bf16 (4 VGPRs)
using f32x4  = __attribute__((ext_vector_type(4))) float;

// async global->LDS, 16B per lane (zero VGPR staging)
__device__ __forceinline__ void load_lds16s(const short* g, short* l) {
  __builtin_amdgcn_global_load_lds(
      (const __attribute__((address_space(1))) unsigned int*)g,
      (__attribute__((address_space(3))) unsigned int*)l, 16, 0, 0);
}

__device__ __forceinline__ unsigned bf16rne(float v) {
  unsigned u = __float_as_uint(v);
  return (u + 0x7FFFu + ((u >> 16) & 1u)) >> 16;
}

// ============ fused prep: prep_x(l1) | hist | relalpha(x2) | prep_w(x2) ======
// All regions independent; branch by blockIdx region. prep_x emits A-frag
// panel order: panel=(row/16)*(K/32)+k/32; lane=(row%16)+((k%32)/8)*16; j=k%8.
__global__ __launch_bounds__(256) void fused_prep(
    const float* __restrict__ x, short* __restrict__ xfh, short* __restrict__ xfl,
    const int* __restrict__ dst, int* __restrict__ deg,
    const float* __restrict__ rel1, const float* __restrict__ We1, const float* __restrict__ ae1,
    const float* __restrict__ rel2, const float* __restrict__ We2, const float* __restrict__ ae2,
    float* __restrict__ tab1, float* __restrict__ tab2,
    const float* __restrict__ W1, short* __restrict__ w1h, short* __restrict__ w1l,
    const float* __restrict__ W2, short* __restrict__ w2h, short* __restrict__ w2l) {
  const int bid = blockIdx.x;
  const int t = threadIdx.x;
  __shared__ float plds[16 * 132];

  if (bid < XB) {
    // ---- prep_x for layer-1 input (K = IN_DIM = 128) ----
    const int K = IN_DIM, LW = K + 4;
    for (int i = t * 4; i < 16 * K; i += 1024) {
      int r = i / K, k = i - r * K;
      *(float4*)&plds[r * LW + k] = *(const float4*)&x[(size_t)(bid * 16 + r) * K + k];
    }
    __syncthreads();
    for (int c = t; c < 2 * K; c += 256) {
      int p_k = c >> 6, l = c & 63;
      int r = l & 15, k0 = p_k * 32 + (l >> 4) * 8;
      unsigned hp[4], lp[4];
#pragma unroll
      for (int q = 0; q < 4; ++q) {
        float v0 = plds[r * LW + k0 + q * 2];
        float v1 = plds[r * LW + k0 + q * 2 + 1];
        unsigned h0 = bf16rne(v0), h1 = bf16rne(v1);
        float l0 = (v0 - __uint_as_float(h0 << 16)) * 256.0f;
        float l1 = (v1 - __uint_as_float(h1 << 16)) * 256.0f;
        hp[q] = h0 | (h1 << 16);
        lp[q] = bf16rne(l0) | (bf16rne(l1) << 16);
      }
      size_t base = ((size_t)(bid * (K >> 5) + p_k) * 64 + l) * 8;
      *(int4*)&xfh[base] = make_int4(hp[0], hp[1], hp[2], hp[3]);
      *(int4*)&xfl[base] = make_int4(lp[0], lp[1], lp[2], lp[3]);
    }
    return;
  }
  if (bid < XB + HB) {
    // ---- hist ----
    const int e = (bid - XB) * 256 + t;
    if (e < N_EDGES) atomicAdd(&deg[dst[e]], 1);
    return;
  }
  if (bid < XB + HB + 128) {
    // ---- relalpha, both layers ----
    const int rb = bid - (XB + HB);
    const int layer = rb >> 6, r = rb & 63;
    const float* rel = layer ? rel2 : rel1;
    const float* We  = layer ? We2  : We1;
    const float* ae  = layer ? ae2  : ae1;
    float* tab       = layer ? tab2 : tab1;
    const int K      = layer ? 64   : IN_DIM;
    float acc = 0.f;
    for (int k = 0; k < K; ++k) acc += rel[(size_t)r * K + k] * We[(size_t)k * HC + t];
    int h = t >> 6, lane = t & 63;
    float p = acc * ae[t];
#pragma unroll
    for (int off = 32; off > 0; off >>= 1) p += __shfl_down(p, off);
    if (lane == 0) tab[r * NHEAD + h] = p;
    return;
  }
  {
    // ---- prep_w (W1: 16 blocks, W2: 8 blocks) ----
    const int wb = bid - (XB + HB + 128);
    const float* W; short* Wh; short* Wl; int K, c;
    if (wb < 16) { W = W1; Wh = w1h; Wl = w1l; K = IN_DIM; c = wb * 256 + t; }
    else         { W = W2; Wh = w2h; Wl = w2l; K = 64;     c = (wb - 16) * 256 + t; }
    const int KP = K >> 5;
    if (c >= 16 * KP * 64) return;
    const int p = c >> 6, l = c & 63;
    const int p_c = p / KP, p_k = p - p_c * KP;
    const int col = p_c * 16 + (l & 15), k0 = p_k * 32 + (l >> 4) * 8;
    unsigned hp[4], lp[4];
#pragma unroll
    for (int q = 0; q < 4; ++q) {
      float v0 = W[(size_t)(k0 + q * 2) * HC + col];
      float v1 = W[(size_t)(k0 + q * 2 + 1) * HC + col];
      unsigned h0 = bf16rne(v0), h1 = bf16rne(v1);
      float l0 = (v0 - __uint_as_float(h0 << 16)) * 256.0f;
      float l1 = (v1 - __uint_as_float(h1 << 16)) * 256.0f;
      hp[q] = h0 | (h1 << 16);
      lp[q] = bf16rne(l0) | (bf16rne(l1) << 16);
    }
    size_t base = (size_t)c * 8;
    *(int4*)&Wh[base] = make_int4(hp[0], hp[1], hp[2], hp[3]);
    *(int4*)&Wl[base] = make_int4(lp[0], lp[1], lp[2], lp[3]);
  }
}

// ============ MFMA GEMM + fused alpha: 64 rows x 128 cols per block ==========
// Split-bf16: xs = Xh@Wh + (Xh@Wl + Xl@Wh)/256. R15-proven structure.
// Grid (ceil(M/64), 2). NOTE (R16 lesson): do NOT append LDS-free work to
// this kernel — the 48KB static LDS reservation taxes every block.
__global__ __launch_bounds__(256, 4) void gemm_mfma(
    const short* __restrict__ Xh, const short* __restrict__ Xl,
    const short* __restrict__ Wh, const short* __restrict__ Wl,
    const float* __restrict__ a_s, const float* __restrict__ a_d,
    __half2* __restrict__ xs16, float* __restrict__ asrc, float* __restrict__ adst,
    int M, int K) {
  __shared__ short lds[2][24 * 512];     // 24KB per buf: [Xh4|Xl4|Wh8|Wl8]
  const int t = threadIdx.x;
  const int wv = t >> 6, l = t & 63;
  const int KP = K >> 5;
  const int pr0 = blockIdx.x * 4;        // row-panel base (64 rows)
  const int pc0 = blockIdx.y * 8;        // col-panel base (128 cols)
  const int c0 = blockIdx.y * 128;

#define STAGE(BI, PK)                                                         \
  {                                                                           \
    _Pragma("unroll")                                                         \
    for (int j = 0; j < 6; ++j) {                                             \
      const int s = wv * 6 + j;                                               \
      const short* srcp;                                                      \
      if (s < 4)       srcp = Xh + (((size_t)(pr0 + s) * KP + (PK)) << 9);    \
      else if (s < 8)  srcp = Xl + (((size_t)(pr0 + s - 4) * KP + (PK)) << 9);\
      else if (s < 16) srcp = Wh + (((size_t)(pc0 + s - 8) * KP + (PK)) << 9);\
      else             srcp = Wl + (((size_t)(pc0 + s - 16) * KP + (PK)) << 9);\
      load_lds16s(srcp + l * 8, &lds[BI][s * 512]);                           \
    }                                                                         \
  }

  f32x4 acc0[8], acc1[8];
#pragma unroll
  for (int i = 0; i < 8; ++i)
#pragma unroll
    for (int c = 0; c < 4; ++c) { acc0[i][c] = 0.f; acc1[i][c] = 0.f; }

  STAGE(0, 0);
  for (int pk = 0; pk < KP; ++pk) {
    const int cur = pk & 1;
    if (pk + 1 < KP) {
      STAGE(cur ^ 1, pk + 1);
      asm volatile("s_waitcnt vmcnt(6)" ::: "memory");
    } else {
      asm volatile("s_waitcnt vmcnt(0)" ::: "memory");
    }
    __builtin_amdgcn_s_barrier();
    __builtin_amdgcn_sched_barrier(0);
    const short8 ah = *(const short8*)&lds[cur][(0 + wv) * 512 + l * 8];
    const short8 al = *(const short8*)&lds[cur][(4 + wv) * 512 + l * 8];
#pragma unroll
    for (int t8 = 0; t8 < 8; ++t8) {
      const short8 bh = *(const short8*)&lds[cur][(8 + t8) * 512 + l * 8];
      const short8 bl = *(const short8*)&lds[cur][(16 + t8) * 512 + l * 8];
      acc0[t8] = __builtin_amdgcn_mfma_f32_16x16x32_bf16(ah, bh, acc0[t8], 0, 0, 0);
      acc1[t8] = __builtin_amdgcn_mfma_f32_16x16x32_bf16(ah, bl, acc1[t8], 0, 0, 0);
      acc1[t8] = __builtin_amdgcn_mfma_f32_16x16x32_bf16(al, bh, acc1[t8], 0, 0, 0);
    }
    asm volatile("" ::: "memory");
    __builtin_amdgcn_s_barrier();
  }
#undef STAGE

  // epilogue: C/D layout col=lane&15, row=(lane>>4)*4+reg (m89-verified)
  const int col_l = l & 15;
  const int row_l = (l >> 4) * 4;
  __half* xsh = (__half*)xs16;
  float asv[8], adv[8];
#pragma unroll
  for (int t8 = 0; t8 < 8; ++t8) {
    asv[t8] = a_s[c0 + t8 * 16 + col_l];
    adv[t8] = a_d[c0 + t8 * 16 + col_l];
  }
  float sp[2][4], dp[2][4];
#pragma unroll
  for (int hl = 0; hl < 2; ++hl)
#pragma unroll
    for (int r = 0; r < 4; ++r) { sp[hl][r] = 0.f; dp[hl][r] = 0.f; }

#pragma unroll
  for (int t8 = 0; t8 < 8; ++t8) {
    const int hl = t8 >> 2;
#pragma unroll
    for (int r = 0; r < 4; ++r) {
      const float v = acc0[t8][r] + acc1[t8][r] * (1.0f / 256.0f);
      const int row = (pr0 + wv) * 16 + row_l + r;
      if (row < M) {
        const int col = c0 + t8 * 16 + col_l;
        xsh[(size_t)row * HC + col] = __float2half(v);
      }
      sp[hl][r] += v * asv[t8];
      dp[hl][r] += v * adv[t8];
    }
  }
#pragma unroll
  for (int off = 1; off < 16; off <<= 1) {
#pragma unroll
    for (int hl = 0; hl < 2; ++hl)
#pragma unroll
      for (int r = 0; r < 4; ++r) {
        sp[hl][r] += __shfl_xor(sp[hl][r], off);
        dp[hl][r] += __shfl_xor(dp[hl][r], off);
      }
  }
  if (col_l == 0) {
#pragma unroll
    for (int hl = 0; hl < 2; ++hl) {
      const int head = blockIdx.y * 2 + hl;
#pragma unroll
      for (int r = 0; r < 4; ++r) {
        const int row = (pr0 + wv) * 16 + row_l + r;
        if (row < M) {
          asrc[row * NHEAD + head] = sp[hl][r];
          adst[row * NHEAD + head] = dp[hl][r];
        }
      }
    }
  }
}

// ============ CSR scan chain ============
__global__ __launch_bounds__(256) void block_sum_kernel(
    const int* __restrict__ deg, int* __restrict__ bsum) {
  int i = blockIdx.x * 256 + threadIdx.x;
  int v = (i < N_NODES) ? deg[i] : 0;
#pragma unroll
  for (int off = 32; off > 0; off >>= 1) v += __shfl_down(v, off);
  __shared__ int w[4];
  if ((threadIdx.x & 63) == 0) w[threadIdx.x >> 6] = v;
  __syncthreads();
  if (threadIdx.x == 0) bsum[blockIdx.x] = w[0] + w[1] + w[2] + w[3];
}

__global__ __launch_bounds__(256) void scan_bsum_kernel(
    const int* __restrict__ bsum, int* __restrict__ boff) {
  __shared__ int s[256];
  int t = threadIdx.x;
  int v = (t < SCAN_B) ? bsum[t] : 0;
  s[t] = v;
  __syncthreads();
  for (int off = 1; off < 256; off <<= 1) {
    int u = (t >= off) ? s[t - off] : 0;
    __syncthreads();
    s[t] += u;
    __syncthreads();
  }
  boff[t] = (t == 0) ? 0 : s[t - 1];
}

__global__ __launch_bounds__(256) void scan_final_kernel(
    const int* __restrict__ deg, const int* __restrict__ boff,
    int* __restrict__ rowptr, int* __restrict__ cursor) {
  __shared__ int s[256];
  int t = threadIdx.x;
  int i = blockIdx.x * 256 + t;
  int v = (i < N_NODES) ? deg[i] : 0;
  s[t] = v;
  __syncthreads();
  for (int off = 1; off < 256; off <<= 1) {
    int u = (t >= off) ? s[t - off] : 0;
    __syncthreads();
    s[t] += u;
    __syncthreads();
  }
  int excl = boff[blockIdx.x] + s[t] - v;
  if (i < N_NODES) {
    rowptr[i] = excl;
    cursor[i] = excl;
  }
  if (t == 0 && blockIdx.x == 0) rowptr[N_NODES] = N_EDGES;
}

// standalone CSR fill: no LDS -> high occupancy (R16 lesson)
__global__ __launch_bounds__(256) void fill_kernel(
    const int* __restrict__ src, const int* __restrict__ dst,
    const int* __restrict__ etype, int* __restrict__ cursor,
    int2* __restrict__ csr_pack) {
  int e = blockIdx.x * blockDim.x + threadIdx.x;
  if (e >= N_EDGES) return;
  int d = dst[e];
  int i = atomicAdd(&cursor[d], 1);
  csr_pack[i] = make_int2(src[e], etype[e]);
}

// ============ fused no-max softmax + fp16 gather: ONE WAVE PER NODE ===========
// mode=1 (layer 1): bias+relu, then split-bf16 store in panel order (K=64,
// KP=2) -> feeds gemm layer 2 directly (prep_x l2 eliminated).
// mode=0 (layer 2): bias, fp32 store to out.
__global__ __launch_bounds__(256) void gat_node_kernel(
    const int* __restrict__ rowptr, const int2* __restrict__ csr,
    const float* __restrict__ asrc, const float* __restrict__ adst,
    const float* __restrict__ tab, const __half2* __restrict__ xs16,
    const float* __restrict__ b, float* __restrict__ out,
    short* __restrict__ oxh, short* __restrict__ oxl, int mode) {
  const int n = (blockIdx.x * blockDim.x + threadIdx.x) >> 6;
  if (n >= N_NODES) return;
  const int lane = threadIdx.x & 63;
  const int hh = lane >> 4;               // head of this lane's 4 cols
  const int cbase = lane << 2;
  const int i0 = rowptr[n], i1 = rowptr[n + 1];
  const float adn = adst[n * NHEAD + hh];
  const float treg = tab[lane * NHEAD + hh];   // lane = rel id (NREL==64)

  float4 acc = make_float4(0.f, 0.f, 0.f, 0.f);
  float den = 0.f;
  int i = i0;
  for (; i + 4 <= i1; i += 4) {
    const int2 p0 = csr[i], p1 = csr[i + 1], p2 = csr[i + 2], p3 = csr[i + 3];
    float l0 = asrc[p0.x * NHEAD + hh] + adn + __shfl(treg, p0.y);
    float l1 = asrc[p1.x * NHEAD + hh] + adn + __shfl(treg, p1.y);
    float l2 = asrc[p2.x * NHEAD + hh] + adn + __shfl(treg, p2.y);
    float l3 = asrc[p3.x * NHEAD + hh] + adn + __shfl(treg, p3.y);
    const uint2 q0 = *(const uint2*)&xs16[((size_t)p0.x * HC + cbase) >> 1];
    const uint2 q1 = *(const uint2*)&xs16[((size_t)p1.x * HC + cbase) >> 1];
    const uint2 q2 = *(const uint2*)&xs16[((size_t)p2.x * HC + cbase) >> 1];
    const uint2 q3 = *(const uint2*)&xs16[((size_t)p3.x * HC + cbase) >> 1];
    l0 = (l0 >= 0.f) ? l0 : NEG_SLOPE * l0;
    l1 = (l1 >= 0.f) ? l1 : NEG_SLOPE * l1;
    l2 = (l2 >= 0.f) ? l2 : NEG_SLOPE * l2;
    l3 = (l3 >= 0.f) ? l3 : NEG_SLOPE * l3;
    const float w0 = __expf(l0), w1 = __expf(l1), w2 = __expf(l2), w3 = __expf(l3);
    den += (w0 + w1) + (w2 + w3);
    const float2 a0 = __half22float2(*(const __half2*)&q0.x), b0 = __half22float2(*(const __half2*)&q0.y);
    const float2 a1 = __half22float2(*(const __half2*)&q1.x), b1 = __half22float2(*(const __half2*)&q1.y);
    const float2 a2 = __half22float2(*(const __half2*)&q2.x), b2 = __half22float2(*(const __half2*)&q2.y);
    const float2 a3 = __half22float2(*(const __half2*)&q3.x), b3 = __half22float2(*(const __half2*)&q3.y);
    acc.x += w0 * a0.x + w1 * a1.x + w2 * a2.x + w3 * a3.x;
    acc.y += w0 * a0.y + w1 * a1.y + w2 * a2.y + w3 * a3.y;
    acc.z += w0 * b0.x + w1 * b1.x + w2 * b2.x + w3 * b3.x;
    acc.w += w0 * b0.y + w1 * b1.y + w2 * b2.y + w3 * b3.y;
  }
  for (; i < i1; ++i) {
    const int2 p = csr[i];
    float l = asrc[p.x * NHEAD + hh] + adn + __shfl(treg, p.y);
    l = (l >= 0.f) ? l : NEG_SLOPE * l;
    const float w = __expf(l);
    const uint2 q = *(const uint2*)&xs16[((size_t)p.x * HC + cbase) >> 1];
    const float2 a = __half22float2(*(const __half2*)&q.x);
    const float2 c = __half22float2(*(const __half2*)&q.y);
    den += w;
    acc.x += w * a.x; acc.y += w * a.y; acc.z += w * c.x; acc.w += w * c.y;
  }

  const float rd = (den > 0.f) ? (0.25f / den) : 0.f;
  float4 y = make_float4(acc.x * rd, acc.y * rd, acc.z * rd, acc.w * rd);
#pragma unroll
  for (int off = 16; off < 64; off <<= 1) {
    y.x += __shfl_xor(y.x, off);
    y.y += __shfl_xor(y.y, off);
    y.z += __shfl_xor(y.z, off);
    y.w += __shfl_xor(y.w, off);
  }
  if (lane < 16) {
    const float4 bb = *(const float4*)&b[lane * 4];
    y.x += bb.x; y.y += bb.y; y.z += bb.z; y.w += bb.w;
    if (mode) {
      // relu + split-bf16, panel-order store (verified mapping, K=64)
      y.x = fmaxf(y.x, 0.f); y.y = fmaxf(y.y, 0.f);
      y.z = fmaxf(y.z, 0.f); y.w = fmaxf(y.w, 0.f);
      unsigned h0 = bf16rne(y.x), h1 = bf16rne(y.y);
      unsigned h2 = bf16rne(y.z), h3 = bf16rne(y.w);
      float l0 = (y.x - __uint_as_float(h0 << 16)) * 256.0f;
      float l1 = (y.y - __uint_as_float(h1 << 16)) * 256.0f;
      float l2 = (y.z - __uint_as_float(h2 << 16)) * 256.0f;
      float l3 = (y.w - __uint_as_float(h3 << 16)) * 256.0f;
      unsigned hp0 = h0 | (h1 << 16), hp1 = h2 | (h3 << 16);
      unsigned lp0 = bf16rne(l0) | (bf16rne(l1) << 16);
      unsigned lp1 = bf16rne(l2) | (bf16rne(l3) << 16);
      const int pk = lane >> 3;                       // k0=4*lane; k0/32
      const int lip = (n & 15) + ((lane >> 1) & 3) * 16;
      const int j0 = (lane & 1) * 4;
      size_t base = ((size_t)((n >> 4) * 2 + pk) * 64 + lip) * 8 + j0;
      *(uint2*)&oxh[base] = make_uint2(hp0, hp1);
      *(uint2*)&oxl[base] = make_uint2(lp0, lp1);
    } else {
      *(float4*)&out[(size_t)n * 64 + lane * 4] = y;
    }
  }
}

extern "C" void kernel_launch(void* const* d_in, const int* in_sizes, int n_in,
                              void* d_out, int out_size, void* d_ws, size_t ws_size,
                              hipStream_t stream) {
  const float* x   = (const float*)d_in[0];
  const int* eidx  = (const int*)d_in[1];
  const int* etype = (const int*)d_in[2];
  const float* rel1 = (const float*)d_in[3];
  const float* W1   = (const float*)d_in[4];
  const float* We1  = (const float*)d_in[5];
  const float* as1  = (const float*)d_in[6];
  const float* ad1  = (const float*)d_in[7];
  const float* ae1  = (const float*)d_in[8];
  const float* b1   = (const float*)d_in[9];
  const float* rel2 = (const float*)d_in[10];
  const float* W2   = (const float*)d_in[11];
  const float* We2  = (const float*)d_in[12];
  const float* as2  = (const float*)d_in[13];
  const float* ad2  = (const float*)d_in[14];
  const float* ae2  = (const float*)d_in[15];
  const float* b2   = (const float*)d_in[16];
  const int* src = eidx;
  const int* dst = eidx + N_EDGES;

  // ---- workspace layout (256B-aligned regions) ----
  char* wsb = (char*)d_ws;
  size_t off = 0;
  auto carve = [&](size_t bytes) { char* p = wsb + off; off = (off + bytes + 255) & ~(size_t)255; return p; };
  __half2* xs16 = (__half2*)carve((size_t)N_NODES * HC * 2);          // 25.6MB
  float* asrc = (float*)carve((size_t)N_NODES * NHEAD * 4);
  float* adst = (float*)carve((size_t)N_NODES * NHEAD * 4);
  float* tab1 = (float*)carve(NREL * NHEAD * 4);
  float* tab2 = (float*)carve(NREL * NHEAD * 4);
  short* xfh  = (short*)carve(((size_t)N_NODES * IN_DIM + 32768) * 2);// 12.9MB
  short* xfl  = (short*)carve(((size_t)N_NODES * IN_DIM + 32768) * 2);
  short* w1h  = (short*)carve(256 * IN_DIM * 2);
  short* w1l  = (short*)carve(256 * IN_DIM * 2);
  short* w2h  = (short*)carve(256 * 64 * 2);
  short* w2l  = (short*)carve(256 * 64 * 2);
  int* deg    = (int*)carve(N_NODES * 4);
  int* rowptr = (int*)carve((N_NODES + 1) * 4);
  int* cursor = (int*)carve(N_NODES * 4);
  int2* csr   = (int2*)carve((size_t)N_EDGES * 8);
  int* bsum   = (int*)carve(256 * 4);
  int* boff   = (int*)carve(256 * 4);

  hipMemsetAsync(deg, 0, N_NODES * sizeof(int), stream);

  // fused prep: prep_x(l1) | hist | relalpha x2 | prep_w x2
  fused_prep<<<XB + HB + 128 + 16 + 8, 256, 0, stream>>>(
      x, xfh, xfl, dst, deg,
      rel1, We1, ae1, rel2, We2, ae2, tab1, tab2,
      W1, w1h, w1l, W2, w2h, w2l);

  block_sum_kernel<<<SCAN_B, 256, 0, stream>>>(deg, bsum);
  scan_bsum_kernel<<<1, 256, 0, stream>>>(bsum, boff);
  scan_final_kernel<<<SCAN_B, 256, 0, stream>>>(deg, boff, rowptr, cursor);
  fill_kernel<<<HB, 256, 0, stream>>>(src, dst, etype, cursor, csr);

  const dim3 gemm_grid((N_NODES + 63) / 64, 2);
  const int GB = (N_NODES * 64 + 255) / 256;   // one wave per node

  // ================= layer 1 =================
  gemm_mfma<<<gemm_grid, 256, 0, stream>>>(xfh, xfl, w1h, w1l, as1, ad1, xs16, asrc, adst, N_NODES, IN_DIM);
  gat_node_kernel<<<GB, 256, 0, stream>>>(rowptr, csr, asrc, adst, tab1, xs16,
                                          b1, nullptr, xfh, xfl, 1);

  // ================= layer 2 =================
  gemm_mfma<<<gemm_grid, 256, 0, stream>>>(xfh, xfl, w2h, w2l, as2, ad2, xs16, asrc, adst, N_NODES, 64);
  gat_node_kernel<<<GB, 256, 0, stream>>>(rowptr, csr, asrc, adst, tab2, xs16,
                                          b2, (float*)d_out, nullptr, nullptr, 0);
}

// Round 18
// 272.939 us; speedup vs baseline: 1.5568x; 1.1093x over previous
//
#include <hip/hip_runtime.h>
#include <hip/hip_bf16.h>
#include <hip/hip_fp16.h>
#include <math.h>

#define N_NODES 50000
#define N_EDGES 800000
#define IN_DIM 128
#define NHEAD 4
#define NREL 64
#define HC 256              // NHEAD * 64 (both layers: H*HID = H*OUT = 256)
#define NEG_SLOPE 0.2f
#define SCAN_B ((N_NODES + 255) / 256)   // 196 blocks
#define XB (N_NODES / 16)                // 3125 prep_x blocks
#define HB ((N_EDGES + 255) / 256)       // 3125 hist/fill blocks

using short8 = __attribute__((ext_vector_type(8))) short;   // 8 bf16 (4 VGPRs)
using f32x4  = __attribute__((ext_vector_type(4))) float;

// async global->LDS, 16B per lane (zero VGPR staging)
__device__ __forceinline__ void load_lds16s(const short* g, short* l) {
  __builtin_amdgcn_global_load_lds(
      (const __attribute__((address_space(1))) unsigned int*)g,
      (__attribute__((address_space(3))) unsigned int*)l, 16, 0, 0);
}

__device__ __forceinline__ unsigned bf16rne(float v) {
  unsigned u = __float_as_uint(v);
  return (u + 0x7FFFu + ((u >> 16) & 1u)) >> 16;
}

// ============ hist + rank: ONE atomic pass for the whole CSR build ===========
// rank[e] = this edge's arrival index among edges sharing its dst. fill then
// places edges with NO atomics (R17 lesson: each device-scope atomic is a
// 64B RMW at the L3 coherence point — ~51MB hidden traffic per 800K pass).
__global__ __launch_bounds__(256) void hist_rank_kernel(
    const int* __restrict__ dst, int* __restrict__ deg,
    unsigned short* __restrict__ rank) {
  int e = blockIdx.x * blockDim.x + threadIdx.x;
  if (e < N_EDGES) {
    int r = atomicAdd(&deg[dst[e]], 1);
    rank[e] = (unsigned short)r;
  }
}

// ============ fused prep: prep_x(l1) | relalpha(x2) | prep_w(x2) ============
// prep_x emits A-frag panel order: panel=(row/16)*(K/32)+k/32;
// lane=(row%16)+((k%32)/8)*16; j=k%8.
__global__ __launch_bounds__(256) void fused_prep(
    const float* __restrict__ x, short* __restrict__ xfh, short* __restrict__ xfl,
    const float* __restrict__ rel1, const float* __restrict__ We1, const float* __restrict__ ae1,
    const float* __restrict__ rel2, const float* __restrict__ We2, const float* __restrict__ ae2,
    float* __restrict__ tab1, float* __restrict__ tab2,
    const float* __restrict__ W1, short* __restrict__ w1h, short* __restrict__ w1l,
    const float* __restrict__ W2, short* __restrict__ w2h, short* __restrict__ w2l) {
  const int bid = blockIdx.x;
  const int t = threadIdx.x;
  __shared__ float plds[16 * 132];

  if (bid < XB) {
    // ---- prep_x for layer-1 input (K = IN_DIM = 128) ----
    const int K = IN_DIM, LW = K + 4;
    for (int i = t * 4; i < 16 * K; i += 1024) {
      int r = i / K, k = i - r * K;
      *(float4*)&plds[r * LW + k] = *(const float4*)&x[(size_t)(bid * 16 + r) * K + k];
    }
    __syncthreads();
    for (int c = t; c < 2 * K; c += 256) {
      int p_k = c >> 6, l = c & 63;
      int r = l & 15, k0 = p_k * 32 + (l >> 4) * 8;
      unsigned hp[4], lp[4];
#pragma unroll
      for (int q = 0; q < 4; ++q) {
        float v0 = plds[r * LW + k0 + q * 2];
        float v1 = plds[r * LW + k0 + q * 2 + 1];
        unsigned h0 = bf16rne(v0), h1 = bf16rne(v1);
        float l0 = (v0 - __uint_as_float(h0 << 16)) * 256.0f;
        float l1 = (v1 - __uint_as_float(h1 << 16)) * 256.0f;
        hp[q] = h0 | (h1 << 16);
        lp[q] = bf16rne(l0) | (bf16rne(l1) << 16);
      }
      size_t base = ((size_t)(bid * (K >> 5) + p_k) * 64 + l) * 8;
      *(int4*)&xfh[base] = make_int4(hp[0], hp[1], hp[2], hp[3]);
      *(int4*)&xfl[base] = make_int4(lp[0], lp[1], lp[2], lp[3]);
    }
    return;
  }
  if (bid < XB + 128) {
    // ---- relalpha, both layers ----
    const int rb = bid - XB;
    const int layer = rb >> 6, r = rb & 63;
    const float* rel = layer ? rel2 : rel1;
    const float* We  = layer ? We2  : We1;
    const float* ae  = layer ? ae2  : ae1;
    float* tab       = layer ? tab2 : tab1;
    const int K      = layer ? 64   : IN_DIM;
    float acc = 0.f;
    for (int k = 0; k < K; ++k) acc += rel[(size_t)r * K + k] * We[(size_t)k * HC + t];
    int h = t >> 6, lane = t & 63;
    float p = acc * ae[t];
#pragma unroll
    for (int off = 32; off > 0; off >>= 1) p += __shfl_down(p, off);
    if (lane == 0) tab[r * NHEAD + h] = p;
    return;
  }
  {
    // ---- prep_w (W1: 16 blocks, W2: 8 blocks) ----
    const int wb = bid - (XB + 128);
    const float* W; short* Wh; short* Wl; int K, c;
    if (wb < 16) { W = W1; Wh = w1h; Wl = w1l; K = IN_DIM; c = wb * 256 + t; }
    else         { W = W2; Wh = w2h; Wl = w2l; K = 64;     c = (wb - 16) * 256 + t; }
    const int KP = K >> 5;
    if (c >= 16 * KP * 64) return;
    const int p = c >> 6, l = c & 63;
    const int p_c = p / KP, p_k = p - p_c * KP;
    const int col = p_c * 16 + (l & 15), k0 = p_k * 32 + (l >> 4) * 8;
    unsigned hp[4], lp[4];
#pragma unroll
    for (int q = 0; q < 4; ++q) {
      float v0 = W[(size_t)(k0 + q * 2) * HC + col];
      float v1 = W[(size_t)(k0 + q * 2 + 1) * HC + col];
      unsigned h0 = bf16rne(v0), h1 = bf16rne(v1);
      float l0 = (v0 - __uint_as_float(h0 << 16)) * 256.0f;
      float l1 = (v1 - __uint_as_float(h1 << 16)) * 256.0f;
      hp[q] = h0 | (h1 << 16);
      lp[q] = bf16rne(l0) | (bf16rne(l1) << 16);
    }
    size_t base = (size_t)c * 8;
    *(int4*)&Wh[base] = make_int4(hp[0], hp[1], hp[2], hp[3]);
    *(int4*)&Wl[base] = make_int4(lp[0], lp[1], lp[2], lp[3]);
  }
}

// ============ MFMA GEMM + fused alpha: 64 rows x 128 cols per block ==========
// Split-bf16: xs = Xh@Wh + (Xh@Wl + Xl@Wh)/256. R15-proven structure.
// Grid (ceil(M/64), 2). R16 lesson: keep LDS-free work OUT of this kernel.
__global__ __launch_bounds__(256, 4) void gemm_mfma(
    const short* __restrict__ Xh, const short* __restrict__ Xl,
    const short* __restrict__ Wh, const short* __restrict__ Wl,
    const float* __restrict__ a_s, const float* __restrict__ a_d,
    __half2* __restrict__ xs16, float* __restrict__ asrc, float* __restrict__ adst,
    int M, int K) {
  __shared__ short lds[2][24 * 512];     // 24KB per buf: [Xh4|Xl4|Wh8|Wl8]
  const int t = threadIdx.x;
  const int wv = t >> 6, l = t & 63;
  const int KP = K >> 5;
  const int pr0 = blockIdx.x * 4;        // row-panel base (64 rows)
  const int pc0 = blockIdx.y * 8;        // col-panel base (128 cols)
  const int c0 = blockIdx.y * 128;

#define STAGE(BI, PK)                                                         \
  {                                                                           \
    _Pragma("unroll")                                                         \
    for (int j = 0; j < 6; ++j) {                                             \
      const int s = wv * 6 + j;                                               \
      const short* srcp;                                                      \
      if (s < 4)       srcp = Xh + (((size_t)(pr0 + s) * KP + (PK)) << 9);    \
      else if (s < 8)  srcp = Xl + (((size_t)(pr0 + s - 4) * KP + (PK)) << 9);\
      else if (s < 16) srcp = Wh + (((size_t)(pc0 + s - 8) * KP + (PK)) << 9);\
      else             srcp = Wl + (((size_t)(pc0 + s - 16) * KP + (PK)) << 9);\
      load_lds16s(srcp + l * 8, &lds[BI][s * 512]);                           \
    }                                                                         \
  }

  f32x4 acc0[8], acc1[8];
#pragma unroll
  for (int i = 0; i < 8; ++i)
#pragma unroll
    for (int c = 0; c < 4; ++c) { acc0[i][c] = 0.f; acc1[i][c] = 0.f; }

  STAGE(0, 0);
  for (int pk = 0; pk < KP; ++pk) {
    const int cur = pk & 1;
    if (pk + 1 < KP) {
      STAGE(cur ^ 1, pk + 1);
      asm volatile("s_waitcnt vmcnt(6)" ::: "memory");
    } else {
      asm volatile("s_waitcnt vmcnt(0)" ::: "memory");
    }
    __builtin_amdgcn_s_barrier();
    __builtin_amdgcn_sched_barrier(0);
    const short8 ah = *(const short8*)&lds[cur][(0 + wv) * 512 + l * 8];
    const short8 al = *(const short8*)&lds[cur][(4 + wv) * 512 + l * 8];
#pragma unroll
    for (int t8 = 0; t8 < 8; ++t8) {
      const short8 bh = *(const short8*)&lds[cur][(8 + t8) * 512 + l * 8];
      const short8 bl = *(const short8*)&lds[cur][(16 + t8) * 512 + l * 8];
      acc0[t8] = __builtin_amdgcn_mfma_f32_16x16x32_bf16(ah, bh, acc0[t8], 0, 0, 0);
      acc1[t8] = __builtin_amdgcn_mfma_f32_16x16x32_bf16(ah, bl, acc1[t8], 0, 0, 0);
      acc1[t8] = __builtin_amdgcn_mfma_f32_16x16x32_bf16(al, bh, acc1[t8], 0, 0, 0);
    }
    asm volatile("" ::: "memory");
    __builtin_amdgcn_s_barrier();
  }
#undef STAGE

  // epilogue: C/D layout col=lane&15, row=(lane>>4)*4+reg (m89-verified)
  const int col_l = l & 15;
  const int row_l = (l >> 4) * 4;
  __half* xsh = (__half*)xs16;
  float asv[8], adv[8];
#pragma unroll
  for (int t8 = 0; t8 < 8; ++t8) {
    asv[t8] = a_s[c0 + t8 * 16 + col_l];
    adv[t8] = a_d[c0 + t8 * 16 + col_l];
  }
  float sp[2][4], dp[2][4];
#pragma unroll
  for (int hl = 0; hl < 2; ++hl)
#pragma unroll
    for (int r = 0; r < 4; ++r) { sp[hl][r] = 0.f; dp[hl][r] = 0.f; }

#pragma unroll
  for (int t8 = 0; t8 < 8; ++t8) {
    const int hl = t8 >> 2;
#pragma unroll
    for (int r = 0; r < 4; ++r) {
      const float v = acc0[t8][r] + acc1[t8][r] * (1.0f / 256.0f);
      const int row = (pr0 + wv) * 16 + row_l + r;
      if (row < M) {
        const int col = c0 + t8 * 16 + col_l;
        xsh[(size_t)row * HC + col] = __float2half(v);
      }
      sp[hl][r] += v * asv[t8];
      dp[hl][r] += v * adv[t8];
    }
  }
#pragma unroll
  for (int off = 1; off < 16; off <<= 1) {
#pragma unroll
    for (int hl = 0; hl < 2; ++hl)
#pragma unroll
      for (int r = 0; r < 4; ++r) {
        sp[hl][r] += __shfl_xor(sp[hl][r], off);
        dp[hl][r] += __shfl_xor(dp[hl][r], off);
      }
  }
  if (col_l == 0) {
#pragma unroll
    for (int hl = 0; hl < 2; ++hl) {
      const int head = blockIdx.y * 2 + hl;
#pragma unroll
      for (int r = 0; r < 4; ++r) {
        const int row = (pr0 + wv) * 16 + row_l + r;
        if (row < M) {
          asrc[row * NHEAD + head] = sp[hl][r];
          adst[row * NHEAD + head] = dp[hl][r];
        }
      }
    }
  }
}

// ============ CSR scan chain ============
__global__ __launch_bounds__(256) void block_sum_kernel(
    const int* __restrict__ deg, int* __restrict__ bsum) {
  int i = blockIdx.x * 256 + threadIdx.x;
  int v = (i < N_NODES) ? deg[i] : 0;
#pragma unroll
  for (int off = 32; off > 0; off >>= 1) v += __shfl_down(v, off);
  __shared__ int w[4];
  if ((threadIdx.x & 63) == 0) w[threadIdx.x >> 6] = v;
  __syncthreads();
  if (threadIdx.x == 0) bsum[blockIdx.x] = w[0] + w[1] + w[2] + w[3];
}

__global__ __launch_bounds__(256) void scan_bsum_kernel(
    const int* __restrict__ bsum, int* __restrict__ boff) {
  __shared__ int s[256];
  int t = threadIdx.x;
  int v = (t < SCAN_B) ? bsum[t] : 0;
  s[t] = v;
  __syncthreads();
  for (int off = 1; off < 256; off <<= 1) {
    int u = (t >= off) ? s[t - off] : 0;
    __syncthreads();
    s[t] += u;
    __syncthreads();
  }
  boff[t] = (t == 0) ? 0 : s[t - 1];
}

__global__ __launch_bounds__(256) void scan_final_kernel(
    const int* __restrict__ deg, const int* __restrict__ boff,
    int* __restrict__ rowptr) {
  __shared__ int s[256];
  int t = threadIdx.x;
  int i = blockIdx.x * 256 + t;
  int v = (i < N_NODES) ? deg[i] : 0;
  s[t] = v;
  __syncthreads();
  for (int off = 1; off < 256; off <<= 1) {
    int u = (t >= off) ? s[t - off] : 0;
    __syncthreads();
    s[t] += u;
    __syncthreads();
  }
  int excl = boff[blockIdx.x] + s[t] - v;
  if (i < N_NODES) rowptr[i] = excl;
  if (t == 0 && blockIdx.x == 0) rowptr[N_NODES] = N_EDGES;
}

// atomic-free CSR fill: position = rowptr[dst] + rank (from hist pass);
// payload packed as src | (etype<<16) (src<65536, etype<64)
__global__ __launch_bounds__(256) void fill_kernel(
    const int* __restrict__ src, const int* __restrict__ dst,
    const int* __restrict__ etype, const unsigned short* __restrict__ rank,
    const int* __restrict__ rowptr, int* __restrict__ csrp) {
  int e = blockIdx.x * blockDim.x + threadIdx.x;
  if (e >= N_EDGES) return;
  int d = dst[e];
  int pos = rowptr[d] + rank[e];
  csrp[pos] = src[e] | (etype[e] << 16);
}

// ============ fused no-max softmax + fp16 gather: ONE WAVE PER NODE ===========
// mode=1 (layer 1): bias+relu, then split-bf16 store in panel order (K=64,
// KP=2) -> feeds gemm layer 2 directly. mode=0 (layer 2): bias, fp32 out.
__global__ __launch_bounds__(256) void gat_node_kernel(
    const int* __restrict__ rowptr, const int* __restrict__ csr,
    const float* __restrict__ asrc, const float* __restrict__ adst,
    const float* __restrict__ tab, const __half2* __restrict__ xs16,
    const float* __restrict__ b, float* __restrict__ out,
    short* __restrict__ oxh, short* __restrict__ oxl, int mode) {
  const int n = (blockIdx.x * blockDim.x + threadIdx.x) >> 6;
  if (n >= N_NODES) return;
  const int lane = threadIdx.x & 63;
  const int hh = lane >> 4;               // head of this lane's 4 cols
  const int cbase = lane << 2;
  const int i0 = rowptr[n], i1 = rowptr[n + 1];
  const float adn = adst[n * NHEAD + hh];
  const float treg = tab[lane * NHEAD + hh];   // lane = rel id (NREL==64)

  float4 acc = make_float4(0.f, 0.f, 0.f, 0.f);
  float den = 0.f;
  int i = i0;
  for (; i + 4 <= i1; i += 4) {
    const int p0 = csr[i], p1 = csr[i + 1], p2 = csr[i + 2], p3 = csr[i + 3];
    const int s0 = p0 & 0xFFFF, s1 = p1 & 0xFFFF, s2 = p2 & 0xFFFF, s3 = p3 & 0xFFFF;
    float l0 = asrc[s0 * NHEAD + hh] + adn + __shfl(treg, p0 >> 16);
    float l1 = asrc[s1 * NHEAD + hh] + adn + __shfl(treg, p1 >> 16);
    float l2 = asrc[s2 * NHEAD + hh] + adn + __shfl(treg, p2 >> 16);
    float l3 = asrc[s3 * NHEAD + hh] + adn + __shfl(treg, p3 >> 16);
    const uint2 q0 = *(const uint2*)&xs16[((size_t)s0 * HC + cbase) >> 1];
    const uint2 q1 = *(const uint2*)&xs16[((size_t)s1 * HC + cbase) >> 1];
    const uint2 q2 = *(const uint2*)&xs16[((size_t)s2 * HC + cbase) >> 1];
    const uint2 q3 = *(const uint2*)&xs16[((size_t)s3 * HC + cbase) >> 1];
    l0 = (l0 >= 0.f) ? l0 : NEG_SLOPE * l0;
    l1 = (l1 >= 0.f) ? l1 : NEG_SLOPE * l1;
    l2 = (l2 >= 0.f) ? l2 : NEG_SLOPE * l2;
    l3 = (l3 >= 0.f) ? l3 : NEG_SLOPE * l3;
    const float w0 = __expf(l0), w1 = __expf(l1), w2 = __expf(l2), w3 = __expf(l3);
    den += (w0 + w1) + (w2 + w3);
    const float2 a0 = __half22float2(*(const __half2*)&q0.x), b0 = __half22float2(*(const __half2*)&q0.y);
    const float2 a1 = __half22float2(*(const __half2*)&q1.x), b1 = __half22float2(*(const __half2*)&q1.y);
    const float2 a2 = __half22float2(*(const __half2*)&q2.x), b2 = __half22float2(*(const __half2*)&q2.y);
    const float2 a3 = __half22float2(*(const __half2*)&q3.x), b3 = __half22float2(*(const __half2*)&q3.y);
    acc.x += w0 * a0.x + w1 * a1.x + w2 * a2.x + w3 * a3.x;
    acc.y += w0 * a0.y + w1 * a1.y + w2 * a2.y + w3 * a3.y;
    acc.z += w0 * b0.x + w1 * b1.x + w2 * b2.x + w3 * b3.x;
    acc.w += w0 * b0.y + w1 * b1.y + w2 * b2.y + w3 * b3.y;
  }
  for (; i < i1; ++i) {
    const int p = csr[i];
    const int s = p & 0xFFFF;
    float l = asrc[s * NHEAD + hh] + adn + __shfl(treg, p >> 16);
    l = (l >= 0.f) ? l : NEG_SLOPE * l;
    const float w = __expf(l);
    const uint2 q = *(const uint2*)&xs16[((size_t)s * HC + cbase) >> 1];
    const float2 a = __half22float2(*(const __half2*)&q.x);
    const float2 c = __half22float2(*(const __half2*)&q.y);
    den += w;
    acc.x += w * a.x; acc.y += w * a.y; acc.z += w * c.x; acc.w += w * c.y;
  }

  const float rd = (den > 0.f) ? (0.25f / den) : 0.f;
  float4 y = make_float4(acc.x * rd, acc.y * rd, acc.z * rd, acc.w * rd);
#pragma unroll
  for (int off = 16; off < 64; off <<= 1) {
    y.x += __shfl_xor(y.x, off);
    y.y += __shfl_xor(y.y, off);
    y.z += __shfl_xor(y.z, off);
    y.w += __shfl_xor(y.w, off);
  }
  if (lane < 16) {
    const float4 bb = *(const float4*)&b[lane * 4];
    y.x += bb.x; y.y += bb.y; y.z += bb.z; y.w += bb.w;
    if (mode) {
      // relu + split-bf16, panel-order store (verified mapping, K=64)
      y.x = fmaxf(y.x, 0.f); y.y = fmaxf(y.y, 0.f);
      y.z = fmaxf(y.z, 0.f); y.w = fmaxf(y.w, 0.f);
      unsigned h0 = bf16rne(y.x), h1 = bf16rne(y.y);
      unsigned h2 = bf16rne(y.z), h3 = bf16rne(y.w);
      float l0 = (y.x - __uint_as_float(h0 << 16)) * 256.0f;
      float l1 = (y.y - __uint_as_float(h1 << 16)) * 256.0f;
      float l2 = (y.z - __uint_as_float(h2 << 16)) * 256.0f;
      float l3 = (y.w - __uint_as_float(h3 << 16)) * 256.0f;
      unsigned hp0 = h0 | (h1 << 16), hp1 = h2 | (h3 << 16);
      unsigned lp0 = bf16rne(l0) | (bf16rne(l1) << 16);
      unsigned lp1 = bf16rne(l2) | (bf16rne(l3) << 16);
      const int pk = lane >> 3;                       // k0=4*lane; k0/32
      const int lip = (n & 15) + ((lane >> 1) & 3) * 16;
      const int j0 = (lane & 1) * 4;
      size_t base = ((size_t)((n >> 4) * 2 + pk) * 64 + lip) * 8 + j0;
      *(uint2*)&oxh[base] = make_uint2(hp0, hp1);
      *(uint2*)&oxl[base] = make_uint2(lp0, lp1);
    } else {
      *(float4*)&out[(size_t)n * 64 + lane * 4] = y;
    }
  }
}

extern "C" void kernel_launch(void* const* d_in, const int* in_sizes, int n_in,
                              void* d_out, int out_size, void* d_ws, size_t ws_size,
                              hipStream_t stream) {
  const float* x   = (const float*)d_in[0];
  const int* eidx  = (const int*)d_in[1];
  const int* etype = (const int*)d_in[2];
  const float* rel1 = (const float*)d_in[3];
  const float* W1   = (const float*)d_in[4];
  const float* We1  = (const float*)d_in[5];
  const float* as1  = (const float*)d_in[6];
  const float* ad1  = (const float*)d_in[7];
  const float* ae1  = (const float*)d_in[8];
  const float* b1   = (const float*)d_in[9];
  const float* rel2 = (const float*)d_in[10];
  const float* W2   = (const float*)d_in[11];
  const float* We2  = (const float*)d_in[12];
  const float* as2  = (const float*)d_in[13];
  const float* ad2  = (const float*)d_in[14];
  const float* ae2  = (const float*)d_in[15];
  const float* b2   = (const float*)d_in[16];
  const int* src = eidx;
  const int* dst = eidx + N_EDGES;

  // ---- workspace layout (256B-aligned regions) ----
  char* wsb = (char*)d_ws;
  size_t off = 0;
  auto carve = [&](size_t bytes) { char* p = wsb + off; off = (off + bytes + 255) & ~(size_t)255; return p; };
  __half2* xs16 = (__half2*)carve((size_t)N_NODES * HC * 2);          // 25.6MB
  float* asrc = (float*)carve((size_t)N_NODES * NHEAD * 4);
  float* adst = (float*)carve((size_t)N_NODES * NHEAD * 4);
  float* tab1 = (float*)carve(NREL * NHEAD * 4);
  float* tab2 = (float*)carve(NREL * NHEAD * 4);
  short* xfh  = (short*)carve(((size_t)N_NODES * IN_DIM + 32768) * 2);// 12.9MB
  short* xfl  = (short*)carve(((size_t)N_NODES * IN_DIM + 32768) * 2);
  short* w1h  = (short*)carve(256 * IN_DIM * 2);
  short* w1l  = (short*)carve(256 * IN_DIM * 2);
  short* w2h  = (short*)carve(256 * 64 * 2);
  short* w2l  = (short*)carve(256 * 64 * 2);
  int* deg    = (int*)carve(N_NODES * 4);
  int* rowptr = (int*)carve((N_NODES + 1) * 4);
  unsigned short* rank = (unsigned short*)carve((size_t)N_EDGES * 2);
  int* csrp   = (int*)carve((size_t)N_EDGES * 4);
  int* bsum   = (int*)carve(256 * 4);
  int* boff   = (int*)carve(256 * 4);

  hipMemsetAsync(deg, 0, N_NODES * sizeof(int), stream);

  // one atomic pass: counts + per-edge ranks
  hist_rank_kernel<<<HB, 256, 0, stream>>>(dst, deg, rank);

  // fused prep: prep_x(l1) | relalpha x2 | prep_w x2
  fused_prep<<<XB + 128 + 16 + 8, 256, 0, stream>>>(
      x, xfh, xfl,
      rel1, We1, ae1, rel2, We2, ae2, tab1, tab2,
      W1, w1h, w1l, W2, w2h, w2l);

  block_sum_kernel<<<SCAN_B, 256, 0, stream>>>(deg, bsum);
  scan_bsum_kernel<<<1, 256, 0, stream>>>(bsum, boff);
  scan_final_kernel<<<SCAN_B, 256, 0, stream>>>(deg, boff, rowptr);
  fill_kernel<<<HB, 256, 0, stream>>>(src, dst, etype, rank, rowptr, csrp);

  const dim3 gemm_grid((N_NODES + 63) / 64, 2);
  const int GB = (N_NODES * 64 + 255) / 256;   // one wave per node

  // ================= layer 1 =================
  gemm_mfma<<<gemm_grid, 256, 0, stream>>>(xfh, xfl, w1h, w1l, as1, ad1, xs16, asrc, adst, N_NODES, IN_DIM);
  gat_node_kernel<<<GB, 256, 0, stream>>>(rowptr, csrp, asrc, adst, tab1, xs16,
                                          b1, nullptr, xfh, xfl, 1);

  // ================= layer 2 =================
  gemm_mfma<<<gemm_grid, 256, 0, stream>>>(xfh, xfl, w2h, w2l, as2, ad2, xs16, asrc, adst, N_NODES, 64);
  gat_node_kernel<<<GB, 256, 0, stream>>>(rowptr, csrp, asrc, adst, tab2, xs16,
                                          b2, (float*)d_out, nullptr, nullptr, 0);
}